// Round 1
// baseline (14623.390 us; speedup 1.0000x reference)
//
#include <hip/hip_runtime.h>
#include <hip/hip_bf16.h>

typedef __bf16 bf16_t;
typedef __bf16 bf16x8 __attribute__((ext_vector_type(8)));
typedef float  f32x4  __attribute__((ext_vector_type(4)));

#define N_    128
#define T_    256
#define D_    512
#define H_    512
#define G4    2048
#define KTOT  1536
#define ZB_ELEMS 196608   /* 48*8*64*8  = 128x1536 in fragment order */
#define WB_PER_CB 49152   /* 1536*32 */

// fragment-ordered index for Z: k in [0,1536), n in [0,128)
__device__ __forceinline__ int zidx(int k, int n) {
  return ((((k >> 5) * 8 + (n >> 4)) * 64) + ((k >> 3) & 3) * 16 + (n & 15)) * 8 + (k & 7);
}

__device__ __forceinline__ float sigf(float x) { return 1.f / (1.f + __expf(-x)); }
__device__ __forceinline__ float tanhfast(float x) {
  float e = __expf(2.f * x);
  return 1.f - 2.f / (e + 1.f);
}

// ---------------- prep: A layouts (bf16), h0/c0, barrier init ----------------
__global__ void prepA_kernel(const float* __restrict__ A, bf16_t* __restrict__ At,
                             bf16_t* __restrict__ Anat, float* __restrict__ cbuf,
                             bf16_t* __restrict__ Zb0, int* __restrict__ bar) {
  int n = blockIdx.x, tid = threadIdx.x;
  if (n == 0 && tid < 18) bar[tid * 32] = 0;
  for (int h = tid; h < H_; h += 256) {
    const float* ar = A + (size_t)(n * H_ + h) * 16;
    float v[16];
    float s = 0.f;
#pragma unroll
    for (int p = 0; p < 16; p++) { v[p] = ar[p]; s += v[p]; }
    s *= (1.f / 16.f);
    cbuf[n * H_ + h] = s;                 // c0 = h0 (f32, exact)
    Zb0[zidx(h, n)] = (bf16_t)s;          // h0 for step 0 GEMM/attention
#pragma unroll
    for (int p = 0; p < 16; p++) {
      Anat[(size_t)(n * H_ + h) * 16 + p] = (bf16_t)v[p];
      At[(size_t)(n * 16 + p) * H_ + h]   = (bf16_t)v[p];
    }
  }
}

// ---------------- prep: fragment-ordered, gate-permuted weights (bf16) -------
// K rows: [0,512)=Wh, [512,1024)=Wattn, [1024,1536)=Wx ; col jp = 4*hcol+gate
__global__ void prepW_kernel(const float* __restrict__ Wh, const float* __restrict__ Wattn,
                             const float* __restrict__ Wx, bf16_t* __restrict__ Wb) {
  int cb = blockIdx.x >> 2;            // 64 column blocks of 32
  int kq = blockIdx.x & 3;             // quarter of K
  int tt = threadIdx.x;
  int hl = tt & 7, gate = (tt >> 3) & 3, ko = tt >> 5;   // 8 x 4 x 8 = 256
  int oc = gate * H_ + cb * 8 + hl;    // original column
  int jpl = hl * 4 + gate;             // permuted col within block
  int wcl = jpl >> 4, c = jpl & 15;
  for (int kb = kq * 48; kb < kq * 48 + 48; kb++) {
    int k = kb * 8 + ko;
    float v;
    if (k < 512)       v = Wh[(size_t)k * G4 + oc];
    else if (k < 1024) v = Wattn[(size_t)(k - 512) * G4 + oc];
    else               v = Wx[(size_t)(k - 1024) * G4 + oc];
    int kk = k >> 5, ch = (k >> 3) & 3, e = k & 7;
    Wb[(size_t)cb * WB_PER_CB + (((kk * 2 + wcl) * 64) + ch * 16 + c) * 8 + e] = (bf16_t)v;
  }
}

// ---------------- 2-level grid barrier (16 leaves x 16 blocks) ---------------
__device__ __forceinline__ void gridbar(int* bar) {
  __syncthreads();
  if (threadIdx.x == 0) {
    int* gen = bar + 17 * 32;
    int g0 = __hip_atomic_load(gen, __ATOMIC_ACQUIRE, __HIP_MEMORY_SCOPE_AGENT);
    int lid = blockIdx.x >> 4;
    int my = __hip_atomic_fetch_add(bar + lid * 32, 1, __ATOMIC_ACQ_REL, __HIP_MEMORY_SCOPE_AGENT);
    if (my == 15) {
      __hip_atomic_store(bar + lid * 32, 0, __ATOMIC_RELAXED, __HIP_MEMORY_SCOPE_AGENT);
      int r = __hip_atomic_fetch_add(bar + 16 * 32, 1, __ATOMIC_ACQ_REL, __HIP_MEMORY_SCOPE_AGENT);
      if (r == 15) {
        __hip_atomic_store(bar + 16 * 32, 0, __ATOMIC_RELAXED, __HIP_MEMORY_SCOPE_AGENT);
        __hip_atomic_fetch_add(gen, 1, __ATOMIC_ACQ_REL, __HIP_MEMORY_SCOPE_AGENT);
      } else {
        while (__hip_atomic_load(gen, __ATOMIC_ACQUIRE, __HIP_MEMORY_SCOPE_AGENT) == g0)
          __builtin_amdgcn_s_sleep(1);
      }
    } else {
      while (__hip_atomic_load(gen, __ATOMIC_ACQUIRE, __HIP_MEMORY_SCOPE_AGENT) == g0)
        __builtin_amdgcn_s_sleep(1);
    }
  }
  __syncthreads();
}

// ---------------- persistent recurrent kernel --------------------------------
__global__ void __launch_bounds__(256, 2)
lstm_kernel(const float* __restrict__ x, const bf16_t* __restrict__ At,
            const bf16_t* __restrict__ Anat, const bf16_t* __restrict__ Wb,
            const float* __restrict__ bvec, float* __restrict__ cbuf,
            bf16_t* __restrict__ Zb, float* __restrict__ out, int* __restrict__ bar) {
  __shared__ bf16_t Wl[32 * 2 * 64 * 8];   // 64 KiB: Wh+Wattn slice, kk 0..31
  __shared__ float hsh[512];
  __shared__ float red[16][16];
  __shared__ float wls[16];

  const int wg = blockIdx.x, tid = threadIdx.x;
  const int cb = wg & 63, sbi = wg >> 6;     // col-block, sample-block(32)
  const int wave = tid >> 6, lane = tid & 63;
  const int wr = wave >> 1, wc = wave & 1;   // 16-row / 16-col quadrant
  const int nb = sbi * 2 + wr;               // 16-sample block index
  const int s  = sbi * 32 + wr * 16 + (lane & 15);    // my epilogue sample
  const int hc = cb * 8 + wc * 4 + (lane >> 4);       // my epilogue h-col
  const int jp = cb * 32 + wc * 16 + (lane & 15);     // my MFMA output col
  const float bias_l = bvec[(jp & 3) * H_ + (jp >> 2)];

  // one-time: stage Wh/Wattn slice into LDS (coalesced b128 copies)
  {
    const bf16x8* src = (const bf16x8*)(Wb + (size_t)cb * WB_PER_CB);
    bf16x8* dst = (bf16x8*)Wl;
    for (int i = tid; i < 4096; i += 256) dst[i] = src[i];
  }
  __syncthreads();

  int cur = 0;
  for (int t = 0; t < T_; t++) {
    bf16_t* Zc = Zb + cur * ZB_ELEMS;

    // ---- phase A: attention + x_t copy (WGs 0..127, sample n=wg) ----
    if (wg < N_) {
      const int n = wg;
      for (int h = tid; h < H_; h += 256) hsh[h] = (float)Zc[zidx(h, n)];
      __syncthreads();
      {
        const int p = tid >> 4, seg = tid & 15;
        const bf16x8* ar = (const bf16x8*)(At + (size_t)(n * 16 + p) * H_ + seg * 32);
        float sacc = 0.f;
#pragma unroll
        for (int v8 = 0; v8 < 4; v8++) {
          bf16x8 av = ar[v8];
#pragma unroll
          for (int e = 0; e < 8; e++) sacc += hsh[seg * 32 + v8 * 8 + e] * (float)av[e];
        }
        red[p][seg] = sacc;
      }
      __syncthreads();
      if (tid < 16) {
        float sc = 0.f;
#pragma unroll
        for (int sg = 0; sg < 16; sg++) sc += red[tid][sg];
        sc *= 0.044194173824159216f;   // 1/sqrt(512)
        float m = sc;
        for (int off = 8; off >= 1; off >>= 1) m = fmaxf(m, __shfl_xor(m, off, 16));
        float e = __expf(sc - m);
        float ssum = e;
        for (int off = 8; off >= 1; off >>= 1) ssum += __shfl_xor(ssum, off, 16);
        wls[tid] = e / ssum;
      }
      __syncthreads();
      float wl[16];
#pragma unroll
      for (int p = 0; p < 16; p++) wl[p] = wls[p];
      for (int h = tid; h < H_; h += 256) {
        const bf16_t* an = Anat + (size_t)(n * H_ + h) * 16;
        float a = 0.f;
#pragma unroll
        for (int p = 0; p < 16; p++) a += (float)an[p] * wl[p];
        Zc[zidx(512 + h, n)]  = (bf16_t)a;                         // attn
        Zc[zidx(1024 + h, n)] = (bf16_t)x[(size_t)(n * T_ + t) * D_ + h];  // x_t
      }
    }

    gridbar(bar);   // attn + x visible everywhere

    // ---- phase B: Z(128x1536) @ W(1536x2048) tile + gates ----
    {
      const bf16x8* Zf  = (const bf16x8*)Zc;
      const bf16x8* Wf  = (const bf16x8*)Wl;
      const bf16x8* Wxf = (const bf16x8*)(Wb + (size_t)cb * WB_PER_CB + 32768);
      f32x4 acc = {0.f, 0.f, 0.f, 0.f};
#pragma unroll 4
      for (int kk = 0; kk < 32; kk++) {
        bf16x8 a  = Zf[(kk * 8 + nb) * 64 + lane];
        bf16x8 bb = Wf[(kk * 2 + wc) * 64 + lane];
        acc = __builtin_amdgcn_mfma_f32_16x16x32_bf16(a, bb, acc, 0, 0, 0);
      }
#pragma unroll 4
      for (int kk = 0; kk < 16; kk++) {
        bf16x8 a  = Zf[((32 + kk) * 8 + nb) * 64 + lane];
        bf16x8 bb = Wxf[(kk * 2 + wc) * 64 + lane];
        acc = __builtin_amdgcn_mfma_f32_16x16x32_bf16(a, bb, acc, 0, 0, 0);
      }
      // gather i,f,o,g quads: dest lane L <- sample (L&15), h-quad (L>>4)
      float gv[4] = {0.f, 0.f, 0.f, 0.f};
      const int srcbase = ((lane >> 2) & 3) * 16 + (lane >> 4) * 4;
#pragma unroll
      for (int rp = 0; rp < 4; rp++) {
        float v = acc[rp] + bias_l;
#pragma unroll
        for (int g = 0; g < 4; g++) {
          float sv = __shfl(v, srcbase + g, 64);
          if ((lane & 3) == rp) gv[g] = sv;
        }
      }
      float co = cbuf[s * H_ + hc];
      float si = sigf(gv[0]), sf = sigf(gv[1]), so = sigf(gv[2]);
      float cn = sf * co + si * tanhfast(gv[3]);
      float hn = so * tanhfast(cn);
      cbuf[s * H_ + hc] = cn;
      out[(size_t)(s * T_ + t) * H_ + hc] = hn;
      Zb[(cur ^ 1) * ZB_ELEMS + zidx(hc, s)] = (bf16_t)hn;   // h for next step
    }

    gridbar(bar);   // h_{t+1} visible before next phase A
    cur ^= 1;
  }
}

// ---------------- host ----------------
extern "C" void kernel_launch(void* const* d_in, const int* in_sizes, int n_in,
                              void* d_out, int out_size, void* d_ws, size_t ws_size,
                              hipStream_t stream) {
  const float* x     = (const float*)d_in[0];
  const float* A     = (const float*)d_in[1];
  const float* Wx    = (const float*)d_in[2];
  const float* Wh    = (const float*)d_in[3];
  const float* Wattn = (const float*)d_in[4];
  const float* bv    = (const float*)d_in[5];
  float* out = (float*)d_out;

  char* ws = (char*)d_ws;
  // ws layout (bytes)
  const size_t ZB_OFF   = 0;         // 2*196608*2        = 786432
  const size_t AT_OFF   = 786432;    // 128*16*512*2      = 2097152
  const size_t ANAT_OFF = 2883584;   // 128*512*16*2      = 2097152
  const size_t WB_OFF   = 4980736;   // 64*49152*2        = 6291456
  const size_t CB_OFF   = 11272192;  // 128*512*4         = 262144
  const size_t BAR_OFF  = 11534336;  // 18*32*4           = 2304
  if (ws_size < BAR_OFF + 4096) return;   // clean fail instead of corruption

  bf16_t* Zb   = (bf16_t*)(ws + ZB_OFF);
  bf16_t* At   = (bf16_t*)(ws + AT_OFF);
  bf16_t* Anat = (bf16_t*)(ws + ANAT_OFF);
  bf16_t* Wb   = (bf16_t*)(ws + WB_OFF);
  float*  cbuf = (float*)(ws + CB_OFF);
  int*    bar  = (int*)(ws + BAR_OFF);

  prepA_kernel<<<dim3(128), dim3(256), 0, stream>>>(A, At, Anat, cbuf, Zb, bar);
  prepW_kernel<<<dim3(256), dim3(256), 0, stream>>>(Wh, Wattn, Wx, Wb);
  lstm_kernel<<<dim3(256), dim3(256), 0, stream>>>(x, At, Anat, Wb, bv, cbuf, Zb, out, bar);
}

// Round 6
// 5961.304 us; speedup vs baseline: 2.4531x; 2.4531x over previous
//
#include <hip/hip_runtime.h>
#include <hip/hip_bf16.h>

typedef __bf16 bf16_t;
typedef __bf16 bf16x8 __attribute__((ext_vector_type(8)));
typedef float  f32x4  __attribute__((ext_vector_type(4)));

#define N_    128
#define T_    256
#define D_    512
#define H_    512
#define G4    2048
#define ZB_ELEMS 131072   /* 32kk*8nb*64*8 = 128x1024 fragment order */
#define WB_PER_CB 32768   /* 1024*32 */

// fragment-ordered index: k in [0,1024), n in [0,128)
__device__ __forceinline__ int zidx(int k, int n) {
  return ((((k >> 5) * 8 + (n >> 4)) * 64) + ((k >> 3) & 3) * 16 + (n & 15)) * 8 + (k & 7);
}

__device__ __forceinline__ float sigf(float x) { return 1.f / (1.f + __expf(-x)); }
__device__ __forceinline__ float tanhfast(float x) {
  float e = __expf(2.f * x);
  return 1.f - 2.f / (e + 1.f);
}

__device__ __forceinline__ void st_u32_llc(unsigned int* p, unsigned int v) {
  __hip_atomic_store(p, v, __ATOMIC_RELAXED, __HIP_MEMORY_SCOPE_AGENT);
}
__device__ __forceinline__ unsigned int pack2bf(float lo, float hi) {
  union { bf16_t h[2]; unsigned int u; } q;
  q.h[0] = (bf16_t)lo; q.h[1] = (bf16_t)hi; return q.u;
}

// ---------------- prep: weights to fragment order (Wh rows 0..512, Wx 512..1024) --
__global__ void prepW_kernel(const float* __restrict__ Wh, const float* __restrict__ Wx,
                             bf16_t* __restrict__ Wb) {
  int cb = blockIdx.x >> 1, kq = blockIdx.x & 1;
  int tt = threadIdx.x;
  int hl = tt & 7, gate = (tt >> 3) & 3, ko = tt >> 5;
  int oc = gate * H_ + cb * 8 + hl;
  int jpl = hl * 4 + gate;
  int wcl = jpl >> 4, c = jpl & 15;
  for (int kb = kq * 64; kb < kq * 64 + 64; kb++) {
    int k = kb * 8 + ko;
    float v = (k < 512) ? Wh[(size_t)k * G4 + oc] : Wx[(size_t)(k - 512) * G4 + oc];
    int kk = k >> 5, ch = (k >> 3) & 3, e = k & 7;
    Wb[(size_t)cb * WB_PER_CB + (((kk * 2 + wcl) * 64) + ch * 16 + c) * 8 + e] = (bf16_t)v;
  }
}

// ---------------- prep: A_sc layout, h0/c0, Zb[0] h+x, S[0] scores, S[1]=0, bar ----
__global__ void prepA_kernel(const float* __restrict__ A, const float* __restrict__ x,
                             bf16_t* __restrict__ A_sc, float* __restrict__ cbuf,
                             bf16_t* __restrict__ Zb, float* __restrict__ S,
                             int* __restrict__ bar) {
  __shared__ float a_ld[8192];   // A[n]: [h][p] f32, 32KB
  __shared__ float h0s[512];
  __shared__ float redb[256 * 16];
  int n = blockIdx.x, tid = threadIdx.x;
  if (n == 0 && tid < 18) bar[tid * 32] = 0;
  if (tid < 16) S[2048 + n * 16 + tid] = 0.f;   // zero S[1]
  for (int i = tid; i < 8192; i += 256) a_ld[i] = A[(size_t)n * 8192 + i];
  __syncthreads();
  for (int h = tid; h < H_; h += 256) {
    float s = 0.f;
#pragma unroll
    for (int p = 0; p < 16; p++) s += a_ld[h * 16 + p];
    s *= (1.f / 16.f);
    h0s[h] = s;
    cbuf[n * H_ + h] = s;
    Zb[zidx(h, n)] = (bf16_t)s;
  }
  // x for t=0
  for (int d = tid; d < D_; d += 256)
    Zb[zidx(512 + d, n)] = (bf16_t)x[(size_t)n * T_ * D_ + d];
  // A_sc[n][cb][p][c] = A[n][cb*8+c][p]
  for (int idx = tid; idx < 8192; idx += 256) {
    int k = idx >> 4, p = idx & 15;
    A_sc[(size_t)n * 8192 + ((k >> 3) * 16 + p) * 8 + (k & 7)] = (bf16_t)a_ld[idx];
  }
  __syncthreads();
  // S[0][n][p] = sum_h h0[h]*A[n][h][p]  (raw, scale applied in softmax)
  float part[16];
#pragma unroll
  for (int p = 0; p < 16; p++) part[p] = 0.f;
  for (int h = tid; h < H_; h += 256) {
    float hv = h0s[h];
#pragma unroll
    for (int p = 0; p < 16; p++) part[p] += hv * a_ld[h * 16 + p];
  }
#pragma unroll
  for (int p = 0; p < 16; p++) redb[tid * 16 + p] = part[p];
  __syncthreads();
  if (tid < 16) {
    float s = 0.f;
    for (int i = 0; i < 256; i++) s += redb[i * 16 + tid];
    S[n * 16 + tid] = s;
  }
}

// ---------------- prep: B[n,p,j] = sum_h A[n,h,p]*Wattn[h,j], stored [n][cb][jl][p] --
__global__ void __launch_bounds__(256) prepB_kernel(const float* __restrict__ Wattn,
                             const bf16_t* __restrict__ A_sc, bf16_t* __restrict__ Bg) {
  __shared__ bf16_t Al[8192];   // [cb][p][c] = 1024 bf16x8
  int n = blockIdx.x >> 2, jpQ = blockIdx.x & 3;
  int tid = threadIdx.x, p = tid & 15, jg = tid >> 4;
  // FIX (round 5 NaN root cause): stage ALL 1024 bf16x8 (was 512 -> upper half
  // of Al uninitialized -> NaN bf16 garbage -> Bg NaN -> output NaN)
  for (int i = tid; i < 1024; i += 256)
    ((bf16x8*)Al)[i] = ((const bf16x8*)(A_sc + (size_t)n * 8192))[i];
  __syncthreads();
  int cbb = jpQ * 16 + jg;
  float acc[32];
#pragma unroll
  for (int j = 0; j < 32; j++) acc[j] = 0.f;
  for (int k = 0; k < 512; k++) {
    float a = (float)Al[((k >> 3) * 16 + p) * 8 + (k & 7)];
    const float* wr = Wattn + (size_t)k * G4 + cbb * 8;
#pragma unroll
    for (int gate = 0; gate < 4; gate++) {
      const float4* w4 = (const float4*)(wr + gate * H_);
      float4 wa = w4[0], wb = w4[1];
      acc[0 * 4 + gate] += a * wa.x; acc[1 * 4 + gate] += a * wa.y;
      acc[2 * 4 + gate] += a * wa.z; acc[3 * 4 + gate] += a * wa.w;
      acc[4 * 4 + gate] += a * wb.x; acc[5 * 4 + gate] += a * wb.y;
      acc[6 * 4 + gate] += a * wb.z; acc[7 * 4 + gate] += a * wb.w;
    }
  }
  bf16_t* dst = Bg + (((size_t)n * 64 + cbb) * 32) * 16 + p;
#pragma unroll
  for (int jj = 0; jj < 32; jj++) dst[jj * 16] = (bf16_t)acc[jj];
}

// ------- fenced 2-level grid barrier (epoch counters; ACQ_REL arrive, ACQUIRE spin) --
__device__ __forceinline__ void gridbar(int* bar) {
  __syncthreads();   // vmcnt(0): this block's stores complete before arrival
  if (threadIdx.x == 0) {
    int* gen = bar + 17 * 32;
    int g0 = __hip_atomic_load(gen, __ATOMIC_ACQUIRE, __HIP_MEMORY_SCOPE_AGENT);
    int lid = blockIdx.x & 15;
    // release: writeback dirty L2 so other XCDs see our h/x/S data
    int my = __hip_atomic_fetch_add(bar + lid * 32, 1, __ATOMIC_ACQ_REL, __HIP_MEMORY_SCOPE_AGENT);
    if ((my & 15) == 15) {
      int r = __hip_atomic_fetch_add(bar + 16 * 32, 1, __ATOMIC_ACQ_REL, __HIP_MEMORY_SCOPE_AGENT);
      if ((r & 15) == 15) {
        __hip_atomic_fetch_add(gen, 1, __ATOMIC_ACQ_REL, __HIP_MEMORY_SCOPE_AGENT);
      } else {
        while (__hip_atomic_load(gen, __ATOMIC_ACQUIRE, __HIP_MEMORY_SCOPE_AGENT) == g0)
          __builtin_amdgcn_s_sleep(2);
      }
    } else {
      while (__hip_atomic_load(gen, __ATOMIC_ACQUIRE, __HIP_MEMORY_SCOPE_AGENT) == g0)
        __builtin_amdgcn_s_sleep(2);
    }
  }
  __syncthreads();
}

// ---------------- persistent recurrent kernel --------------------------------
__global__ void __launch_bounds__(256, 2)
lstm_kernel(const float* __restrict__ x, const bf16_t* __restrict__ A_sc,
            const bf16_t* __restrict__ Wb, const bf16_t* __restrict__ Bg,
            const float* __restrict__ bvec, const float* __restrict__ cbuf,
            bf16_t* __restrict__ Zb, float* __restrict__ S,
            float* __restrict__ out, int* __restrict__ bar) {
  __shared__ bf16_t Wl[32768];        // 64KB [kk 0..31][wc][64][8]
  __shared__ float hsh[32 * 8];
  __shared__ float wls[32 * 16];

  const int wg = blockIdx.x, tid = threadIdx.x;
  const int cb = wg & 63, sbi = wg >> 6;
  const int wave = tid >> 6, lane = tid & 63;
  const int wr = wave >> 1, wc = wave & 1;
  const int nb = sbi * 2 + wr;
  const int s  = sbi * 32 + wr * 16 + (lane & 15);
  const int hc = cb * 8 + wc * 4 + (lane >> 4);
  const int jp = cb * 32 + wc * 16 + (lane & 15);
  const float bias_l = bvec[(jp & 3) * H_ + (jp >> 2)];
  const int jl = wc * 16 + (lane & 15);

  // one-time LDS staging: W slice only (64KB) -> 2 blocks/CU co-residency
  {
    const bf16x8* src = (const bf16x8*)(Wb + (size_t)cb * WB_PER_CB);
    bf16x8* dst = (bf16x8*)Wl;
    for (int i = tid; i < 4096; i += 256) dst[i] = src[i];
  }
  float creg = cbuf[s * H_ + hc];   // c lives in a register for all 256 steps
  __syncthreads();

  int cur = 0;
  for (int t = 0; t < T_; t++) {
    const bf16_t* Zc = Zb + cur * ZB_ELEMS;
    bf16_t* Zn = Zb + (cur ^ 1) * ZB_ELEMS;
    const int cur3 = t % 3, nxt3 = (t + 1) % 3, z3 = (t + 2) % 3;

    // zero my slice of S[(t+2)%3] — atomic store (performed at LLC) so no
    // dirty local-L2 line can later clobber other XCDs' atomicAdds
    if (tid < 8) st_u32_llc((unsigned int*)(S + z3 * 2048 + wg * 8 + tid), 0u);

    // stage x_{t+1} fragments into Zn (this WG's 8 K-rows, its 32 samples)
    if (t + 1 < T_ && tid < 128) {
      int nl = tid >> 2, e2 = (tid & 3) * 2;
      int n = sbi * 32 + nl;
      const float* xp = x + ((size_t)n * T_ + (t + 1)) * D_ + cb * 8 + e2;
      *(unsigned int*)(Zn + zidx(512 + cb * 8 + e2, n)) = pack2bf(xp[0], xp[1]);
    }

    // softmax for my 32 samples (8 per wave, redundant across cb — cheap)
    if ((tid & 63) < 8) {
      int nl = wave * 8 + (tid & 63);
      int ng = sbi * 32 + nl;
      float r[16];
#pragma unroll
      for (int p = 0; p < 16; p++)
        r[p] = S[cur3 * 2048 + ng * 16 + p] * 0.044194173824159216f;
      float m = r[0];
#pragma unroll
      for (int p = 1; p < 16; p++) m = fmaxf(m, r[p]);
      float ssum = 0.f;
#pragma unroll
      for (int p = 0; p < 16; p++) { r[p] = __expf(r[p] - m); ssum += r[p]; }
      float inv = 1.f / ssum;
#pragma unroll
      for (int p = 0; p < 16; p++) wls[nl * 16 + p] = r[p] * inv;
    }

    // GEMM: [h|x](32 samples x 1024) @ W(1024 x 32 cols) — kk 0..31 is ALL of K
    f32x4 acc = {0.f, 0.f, 0.f, 0.f};
    {
      const bf16x8* Zf = (const bf16x8*)Zc;
      const bf16x8* Wf = (const bf16x8*)Wl;
#pragma unroll 8
      for (int kk = 0; kk < 32; kk++) {
        bf16x8 a = Zf[(kk * 8 + nb) * 64 + lane];
        bf16x8 b = Wf[(kk * 2 + wc) * 64 + lane];
        acc = __builtin_amdgcn_mfma_f32_16x16x32_bf16(a, b, acc, 0, 0, 0);
      }
    }
    __syncthreads();   // wls ready

    // + w@B + bias (per acc row = sample); B slice read from L2-resident Bg
    {
      const int nl0 = wr * 16 + ((lane >> 4) << 2);
#pragma unroll
      for (int rp = 0; rp < 4; rp++) {
        int nl = nl0 + rp;
        const bf16x8* bl = (const bf16x8*)(Bg +
            (((size_t)(sbi * 32 + nl) * 64 + cb) * 32 + jl) * 16);
        bf16x8 b0 = bl[0], b1 = bl[1];
        const float* wn = wls + nl * 16;
        float add = 0.f;
#pragma unroll
        for (int p = 0; p < 8; p++) add += wn[p] * (float)b0[p];
#pragma unroll
        for (int p = 0; p < 8; p++) add += wn[8 + p] * (float)b1[p];
        acc[rp] += add + bias_l;
      }
    }

    // gather i,f,o,g quads
    float gv[4] = {0.f, 0.f, 0.f, 0.f};
    const int srcbase = ((lane >> 2) & 3) * 16 + (lane >> 4) * 4;
#pragma unroll
    for (int rp = 0; rp < 4; rp++) {
      float v = acc[rp];
#pragma unroll
      for (int g = 0; g < 4; g++) {
        float sv = __shfl(v, srcbase + g, 64);
        if ((lane & 3) == rp) gv[g] = sv;
      }
    }

    // gates, state update, outputs
    float si = sigf(gv[0]), sf = sigf(gv[1]), so = sigf(gv[2]);
    float cn = sf * creg + si * tanhfast(gv[3]);
    float hn = so * tanhfast(cn);
    creg = cn;
    __builtin_nontemporal_store(hn, out + ((size_t)s * T_ + t) * H_ + hc);

    // h_{t+1} to Zn (paired bf16 -> u32 store; flushed by barrier release)
    {
      union { bf16_t h; unsigned short u; } cvt; cvt.h = (bf16_t)hn;
      unsigned int hbits = cvt.u;
      unsigned int other = __shfl(hbits, (lane + 16) & 63, 64);
      if (((lane >> 4) & 1) == 0)
        *(unsigned int*)(Zn + zidx(hc, s)) = hbits | (other << 16);
    }
    hsh[(s & 31) * 8 + (hc & 7)] = hn;
    __syncthreads();   // hsh ready

    // partial scores for t+1: my 8 h-cols x my 32 samples
    if (t + 1 < T_) {
      float* Sn = S + nxt3 * 2048;
#pragma unroll
      for (int u = 0; u < 2; u++) {
        int idx = tid + u * 256;
        int nl = idx >> 4, p = idx & 15;
        int ng = sbi * 32 + nl;
        const bf16x8 av = *(const bf16x8*)(A_sc + ((size_t)ng * 64 + cb) * 128 + p * 8);
        float part = 0.f;
#pragma unroll
        for (int c = 0; c < 8; c++) part += hsh[nl * 8 + c] * (float)av[c];
        atomicAdd(Sn + ng * 16 + p, part);
      }
    }

    gridbar(bar);
    cur ^= 1;
  }
}

// ---------------- host ----------------
extern "C" void kernel_launch(void* const* d_in, const int* in_sizes, int n_in,
                              void* d_out, int out_size, void* d_ws, size_t ws_size,
                              hipStream_t stream) {
  const float* x     = (const float*)d_in[0];
  const float* A     = (const float*)d_in[1];
  const float* Wx    = (const float*)d_in[2];
  const float* Wh    = (const float*)d_in[3];
  const float* Wattn = (const float*)d_in[4];
  const float* bv    = (const float*)d_in[5];
  float* out = (float*)d_out;

  char* ws = (char*)d_ws;
  // ws layout (bytes) — sync state FIRST so array overflows can't corrupt it
  const size_t BAR_OFF = 0;          // 18*32*4         = 2304   (pad to 4096)
  const size_t S_OFF   = 4096;       // 3*2048*4        = 24576
  const size_t CB_OFF  = 28672;      // 128*512*4       = 262144
  const size_t ZB_OFF  = 290816;     // 2*131072*2      = 524288
  const size_t ASC_OFF = 815104;     // 128*8192*2      = 2097152
  const size_t WB_OFF  = 2912256;    // 64*32768*2      = 4194304
  const size_t BG_OFF  = 7106560;    // 128*64*32*16 el * 2B = 8388608
  const size_t WS_NEED = 15495168;   // BG_OFF + 8388608
  if (ws_size < WS_NEED) return;     // clean fail instead of corruption

  int*    bar  = (int*)(ws + BAR_OFF);
  float*  S    = (float*)(ws + S_OFF);
  float*  cbuf = (float*)(ws + CB_OFF);
  bf16_t* Zb   = (bf16_t*)(ws + ZB_OFF);
  bf16_t* A_sc = (bf16_t*)(ws + ASC_OFF);
  bf16_t* Wb   = (bf16_t*)(ws + WB_OFF);
  bf16_t* Bg   = (bf16_t*)(ws + BG_OFF);

  prepW_kernel<<<dim3(128), dim3(256), 0, stream>>>(Wh, Wx, Wb);
  prepA_kernel<<<dim3(128), dim3(256), 0, stream>>>(A, x, A_sc, cbuf, Zb, S, bar);
  prepB_kernel<<<dim3(512), dim3(256), 0, stream>>>(Wattn, A_sc, Bg);
  lstm_kernel<<<dim3(256), dim3(256), 0, stream>>>(x, A_sc, Wb, Bg, bv, cbuf, Zb, S, out, bar);
}

// Round 7
// 2740.914 us; speedup vs baseline: 5.3352x; 2.1749x over previous
//
#include <hip/hip_runtime.h>
#include <hip/hip_bf16.h>

typedef __bf16 bf16_t;
typedef __bf16 bf16x8 __attribute__((ext_vector_type(8)));
typedef float  f32x4  __attribute__((ext_vector_type(4)));

#define N_    128
#define T_    256
#define D_    512
#define H_    512
#define G4    2048
#define ZB_ELEMS 131072   /* 32kk*8nb*64*8 = 128x1024 fragment order */
#define WB_PER_CB 32768   /* 1024*32 */

// fragment-ordered index: k in [0,1024), n in [0,128)
__device__ __forceinline__ int zidx(int k, int n) {
  return ((((k >> 5) * 8 + (n >> 4)) * 64) + ((k >> 3) & 3) * 16 + (n & 15)) * 8 + (k & 7);
}

__device__ __forceinline__ float sigf(float x) { return 1.f / (1.f + __expf(-x)); }
__device__ __forceinline__ float tanhfast(float x) {
  float e = __expf(2.f * x);
  return 1.f - 2.f / (e + 1.f);
}

// ---- LLC-coherent access (agent-scope relaxed atomics -> sc1, no L2 wb/inv) ----
__device__ __forceinline__ bf16x8 ld_frag_llc(const bf16_t* p) {
  unsigned long long lo = __hip_atomic_load((const unsigned long long*)p,
      __ATOMIC_RELAXED, __HIP_MEMORY_SCOPE_AGENT);
  unsigned long long hi = __hip_atomic_load(((const unsigned long long*)p) + 1,
      __ATOMIC_RELAXED, __HIP_MEMORY_SCOPE_AGENT);
  union { unsigned long long q[2]; bf16x8 v; } u; u.q[0] = lo; u.q[1] = hi; return u.v;
}
__device__ __forceinline__ float ld_f32_llc(const float* p) {
  return __hip_atomic_load(p, __ATOMIC_RELAXED, __HIP_MEMORY_SCOPE_AGENT);
}
__device__ __forceinline__ void st_u32_llc(unsigned int* p, unsigned int v) {
  __hip_atomic_store(p, v, __ATOMIC_RELAXED, __HIP_MEMORY_SCOPE_AGENT);
}
__device__ __forceinline__ int ld_i32_llc(const int* p) {
  return __hip_atomic_load(p, __ATOMIC_RELAXED, __HIP_MEMORY_SCOPE_AGENT);
}
__device__ __forceinline__ unsigned int pack2bf(float lo, float hi) {
  union { bf16_t h[2]; unsigned int u; } q;
  q.h[0] = (bf16_t)lo; q.h[1] = (bf16_t)hi; return q.u;
}

// ---------------- prep: weights to fragment order (Wh rows 0..512, Wx 512..1024) --
__global__ void prepW_kernel(const float* __restrict__ Wh, const float* __restrict__ Wx,
                             bf16_t* __restrict__ Wb) {
  int cb = blockIdx.x >> 1, kq = blockIdx.x & 1;
  int tt = threadIdx.x;
  int hl = tt & 7, gate = (tt >> 3) & 3, ko = tt >> 5;
  int oc = gate * H_ + cb * 8 + hl;
  int jpl = hl * 4 + gate;
  int wcl = jpl >> 4, c = jpl & 15;
  for (int kb = kq * 64; kb < kq * 64 + 64; kb++) {
    int k = kb * 8 + ko;
    float v = (k < 512) ? Wh[(size_t)k * G4 + oc] : Wx[(size_t)(k - 512) * G4 + oc];
    int kk = k >> 5, ch = (k >> 3) & 3, e = k & 7;
    Wb[(size_t)cb * WB_PER_CB + (((kk * 2 + wcl) * 64) + ch * 16 + c) * 8 + e] = (bf16_t)v;
  }
}

// ---------------- prep: A_sc layout, h0/c0, Zb[0] h+x, S[0] scores, S[1]=0, bar ----
__global__ void prepA_kernel(const float* __restrict__ A, const float* __restrict__ x,
                             bf16_t* __restrict__ A_sc, float* __restrict__ cbuf,
                             bf16_t* __restrict__ Zb, float* __restrict__ S,
                             int* __restrict__ bar) {
  __shared__ float a_ld[8192];   // A[n]: [h][p] f32, 32KB
  __shared__ float h0s[512];
  __shared__ float redb[256 * 16];
  int n = blockIdx.x, tid = threadIdx.x;
  if (n == 0 && tid < 34) bar[tid * 32] = 0;   // leafctr[16], rootctr, gen_root, gen_leaf[16]
  if (tid < 16) S[2048 + n * 16 + tid] = 0.f;   // zero S[1]
  for (int i = tid; i < 8192; i += 256) a_ld[i] = A[(size_t)n * 8192 + i];
  __syncthreads();
  for (int h = tid; h < H_; h += 256) {
    float s = 0.f;
#pragma unroll
    for (int p = 0; p < 16; p++) s += a_ld[h * 16 + p];
    s *= (1.f / 16.f);
    h0s[h] = s;
    cbuf[n * H_ + h] = s;
    Zb[zidx(h, n)] = (bf16_t)s;
  }
  // x for t=0
  for (int d = tid; d < D_; d += 256)
    Zb[zidx(512 + d, n)] = (bf16_t)x[(size_t)n * T_ * D_ + d];
  // A_sc[n][cb][p][c] = A[n][cb*8+c][p]
  for (int idx = tid; idx < 8192; idx += 256) {
    int k = idx >> 4, p = idx & 15;
    A_sc[(size_t)n * 8192 + ((k >> 3) * 16 + p) * 8 + (k & 7)] = (bf16_t)a_ld[idx];
  }
  __syncthreads();
  // S[0][n][p] = sum_h h0[h]*A[n][h][p]  (raw, scale applied in softmax)
  float part[16];
#pragma unroll
  for (int p = 0; p < 16; p++) part[p] = 0.f;
  for (int h = tid; h < H_; h += 256) {
    float hv = h0s[h];
#pragma unroll
    for (int p = 0; p < 16; p++) part[p] += hv * a_ld[h * 16 + p];
  }
#pragma unroll
  for (int p = 0; p < 16; p++) redb[tid * 16 + p] = part[p];
  __syncthreads();
  if (tid < 16) {
    float s = 0.f;
    for (int i = 0; i < 256; i++) s += redb[i * 16 + tid];
    S[n * 16 + tid] = s;
  }
}

// ---------------- prep: B[n,p,j] = sum_h A[n,h,p]*Wattn[h,j], stored [n][cb][jl][p] --
__global__ void __launch_bounds__(256) prepB_kernel(const float* __restrict__ Wattn,
                             const bf16_t* __restrict__ A_sc, bf16_t* __restrict__ Bg) {
  __shared__ bf16_t Al[8192];   // [cb][p][c] = 1024 bf16x8 (FULLY staged — round-5 fix)
  int n = blockIdx.x >> 2, jpQ = blockIdx.x & 3;
  int tid = threadIdx.x, p = tid & 15, jg = tid >> 4;
  for (int i = tid; i < 1024; i += 256)
    ((bf16x8*)Al)[i] = ((const bf16x8*)(A_sc + (size_t)n * 8192))[i];
  __syncthreads();
  int cbb = jpQ * 16 + jg;
  float acc[32];
#pragma unroll
  for (int j = 0; j < 32; j++) acc[j] = 0.f;
  for (int k = 0; k < 512; k++) {
    float a = (float)Al[((k >> 3) * 16 + p) * 8 + (k & 7)];
    const float* wr = Wattn + (size_t)k * G4 + cbb * 8;
#pragma unroll
    for (int gate = 0; gate < 4; gate++) {
      const float4* w4 = (const float4*)(wr + gate * H_);
      float4 wa = w4[0], wb = w4[1];
      acc[0 * 4 + gate] += a * wa.x; acc[1 * 4 + gate] += a * wa.y;
      acc[2 * 4 + gate] += a * wa.z; acc[3 * 4 + gate] += a * wa.w;
      acc[4 * 4 + gate] += a * wb.x; acc[5 * 4 + gate] += a * wb.y;
      acc[6 * 4 + gate] += a * wb.z; acc[7 * 4 + gate] += a * wb.w;
    }
  }
  bf16_t* dst = Bg + (((size_t)n * 64 + cbb) * 32) * 16 + p;
#pragma unroll
  for (int jj = 0; jj < 32; jj++) dst[jj * 16] = (bf16_t)acc[jj];
}

// ---- fence-free 2-level barrier with tree wake (all relaxed; sc1 data path) ----
// g0r/g0l are this episode's epoch values, captured at STEP START (their loads
// complete via the step's intervening __syncthreads vmcnt drains).
__device__ __forceinline__ void gridbar(int* bar, int g0r, int g0l) {
  __syncthreads();   // vmcnt(0): all this block's sc1 stores are in LLC
  if (threadIdx.x == 0) {
    const int leaf = blockIdx.x >> 4;               // 16 leaves x 16 WGs
    int* leafctr  = bar + leaf * 32;
    int* rootctr  = bar + 16 * 32;
    int* gen_root = bar + 17 * 32;
    int* gen_leaf = bar + (18 + leaf) * 32;
    int my = __hip_atomic_fetch_add(leafctr, 1, __ATOMIC_RELAXED, __HIP_MEMORY_SCOPE_AGENT);
    if ((my & 15) == 15) {                          // leaf winner
      int r = __hip_atomic_fetch_add(rootctr, 1, __ATOMIC_RELAXED, __HIP_MEMORY_SCOPE_AGENT);
      if ((r & 15) == 15) {                         // root winner: flip epoch
        __hip_atomic_fetch_add(gen_root, 1, __ATOMIC_RELAXED, __HIP_MEMORY_SCOPE_AGENT);
      } else {
        while (ld_i32_llc(gen_root) == g0r) __builtin_amdgcn_s_sleep(2);
      }
      __hip_atomic_fetch_add(gen_leaf, 1, __ATOMIC_RELAXED, __HIP_MEMORY_SCOPE_AGENT);
    } else {
      while (ld_i32_llc(gen_leaf) == g0l) __builtin_amdgcn_s_sleep(2);
    }
  }
  __syncthreads();
}

// ---------------- persistent recurrent kernel --------------------------------
__global__ void __launch_bounds__(256, 2)
lstm_kernel(const float* __restrict__ x, const bf16_t* __restrict__ A_sc,
            const bf16_t* __restrict__ Wb, const bf16_t* __restrict__ Bg,
            const float* __restrict__ bvec, const float* __restrict__ cbuf,
            bf16_t* __restrict__ Zb, float* __restrict__ S,
            float* __restrict__ out, int* __restrict__ bar) {
  __shared__ bf16_t Wl[32768];        // 64KB [kk 0..31][wc][64][8]
  __shared__ float hsh[32 * 8];
  __shared__ float wls[32 * 16];

  const int wg = blockIdx.x, tid = threadIdx.x;
  const int cb = wg & 63, sbi = wg >> 6;
  const int wave = tid >> 6, lane = tid & 63;
  const int wr = wave >> 1, wc = wave & 1;
  const int nb = sbi * 2 + wr;
  const int s  = sbi * 32 + wr * 16 + (lane & 15);
  const int hc = cb * 8 + wc * 4 + (lane >> 4);
  const int jp = cb * 32 + wc * 16 + (lane & 15);
  const float bias_l = bvec[(jp & 3) * H_ + (jp >> 2)];
  const int jl = wc * 16 + (lane & 15);

  // one-time LDS staging: W slice only (64KB) -> 2 blocks/CU co-residency
  {
    const bf16x8* src = (const bf16x8*)(Wb + (size_t)cb * WB_PER_CB);
    bf16x8* dst = (bf16x8*)Wl;
    for (int i = tid; i < 4096; i += 256) dst[i] = src[i];
  }
  float creg = cbuf[s * H_ + hc];   // c lives in a register for all 256 steps
  __syncthreads();

  int cur = 0;
  for (int t = 0; t < T_; t++) {
    const bf16_t* Zc = Zb + cur * ZB_ELEMS;
    bf16_t* Zn = Zb + (cur ^ 1) * ZB_ELEMS;
    const int cur3 = t % 3, nxt3 = (t + 1) % 3, z3 = (t + 2) % 3;

    // capture this episode's epochs EARLY (completed by later syncthreads;
    // asm barrier pins them against sinking past the arrival fetch_add)
    int g0r = 0, g0l = 0;
    if (tid == 0) {
      g0r = ld_i32_llc(bar + 17 * 32);
      g0l = ld_i32_llc(bar + (18 + (wg >> 4)) * 32);
    }
    asm volatile("" ::: "memory");

    // zero my slice of S[(t+2)%3] (sc1 store, lands at LLC)
    if (tid < 8) st_u32_llc((unsigned int*)(S + z3 * 2048 + wg * 8 + tid), 0u);

    // stage x_{t+1} fragments into Zn (this WG's 8 K-rows, its 32 samples)
    if (t + 1 < T_ && tid < 128) {
      int nl = tid >> 2, e2 = (tid & 3) * 2;
      int n = sbi * 32 + nl;
      const float* xp = x + ((size_t)n * T_ + (t + 1)) * D_ + cb * 8 + e2;
      st_u32_llc((unsigned int*)(Zn + zidx(512 + cb * 8 + e2, n)), pack2bf(xp[0], xp[1]));
    }

    // softmax for my 32 samples (8 per wave, redundant across cb — cheap)
    if ((tid & 63) < 8) {
      int nl = wave * 8 + (tid & 63);
      int ng = sbi * 32 + nl;
      float r[16];
#pragma unroll
      for (int p = 0; p < 16; p++)
        r[p] = ld_f32_llc(S + cur3 * 2048 + ng * 16 + p) * 0.044194173824159216f;
      float m = r[0];
#pragma unroll
      for (int p = 1; p < 16; p++) m = fmaxf(m, r[p]);
      float ssum = 0.f;
#pragma unroll
      for (int p = 0; p < 16; p++) { r[p] = __expf(r[p] - m); ssum += r[p]; }
      float inv = 1.f / ssum;
#pragma unroll
      for (int p = 0; p < 16; p++) wls[nl * 16 + p] = r[p] * inv;
    }

    // GEMM: [h|x](32 samples x 1024) @ W(1024 x 32 cols); Z via sc1 (LLC-fresh)
    f32x4 acc = {0.f, 0.f, 0.f, 0.f};
    {
      const bf16x8* Wf = (const bf16x8*)Wl;
#pragma unroll 8
      for (int kk = 0; kk < 32; kk++) {
        bf16x8 a = ld_frag_llc(Zc + ((size_t)(kk * 8 + nb) * 64 + lane) * 8);
        bf16x8 b = Wf[(kk * 2 + wc) * 64 + lane];
        acc = __builtin_amdgcn_mfma_f32_16x16x32_bf16(a, b, acc, 0, 0, 0);
      }
    }
    __syncthreads();   // wls ready

    // + w@B + bias; Bg is read-only -> normal loads, L2 stays warm (no inv!)
    {
      const int nl0 = wr * 16 + ((lane >> 4) << 2);
#pragma unroll
      for (int rp = 0; rp < 4; rp++) {
        int nl = nl0 + rp;
        const bf16x8* bl = (const bf16x8*)(Bg +
            (((size_t)(sbi * 32 + nl) * 64 + cb) * 32 + jl) * 16);
        bf16x8 b0 = bl[0], b1 = bl[1];
        const float* wn = wls + nl * 16;
        float add = 0.f;
#pragma unroll
        for (int p = 0; p < 8; p++) add += wn[p] * (float)b0[p];
#pragma unroll
        for (int p = 0; p < 8; p++) add += wn[8 + p] * (float)b1[p];
        acc[rp] += add + bias_l;
      }
    }

    // gather i,f,o,g quads
    float gv[4] = {0.f, 0.f, 0.f, 0.f};
    const int srcbase = ((lane >> 2) & 3) * 16 + (lane >> 4) * 4;
#pragma unroll
    for (int rp = 0; rp < 4; rp++) {
      float v = acc[rp];
#pragma unroll
      for (int g = 0; g < 4; g++) {
        float sv = __shfl(v, srcbase + g, 64);
        if ((lane & 3) == rp) gv[g] = sv;
      }
    }

    // gates, state update, outputs
    float si = sigf(gv[0]), sf = sigf(gv[1]), so = sigf(gv[2]);
    float cn = sf * creg + si * tanhfast(gv[3]);
    float hn = so * tanhfast(cn);
    creg = cn;
    __builtin_nontemporal_store(hn, out + ((size_t)s * T_ + t) * H_ + hc);

    // h_{t+1} to Zn (paired bf16 -> u32 sc1 store)
    {
      union { bf16_t h; unsigned short u; } cvt; cvt.h = (bf16_t)hn;
      unsigned int hbits = cvt.u;
      unsigned int other = __shfl(hbits, (lane + 16) & 63, 64);
      if (((lane >> 4) & 1) == 0)
        st_u32_llc((unsigned int*)(Zn + zidx(hc, s)), hbits | (other << 16));
    }
    hsh[(s & 31) * 8 + (hc & 7)] = hn;
    __syncthreads();   // hsh ready

    // partial scores for t+1: my 8 h-cols x my 32 samples (A_sc read-only, L2-warm)
    if (t + 1 < T_) {
      float* Sn = S + nxt3 * 2048;
#pragma unroll
      for (int u = 0; u < 2; u++) {
        int idx = tid + u * 256;
        int nl = idx >> 4, p = idx & 15;
        int ng = sbi * 32 + nl;
        const bf16x8 av = *(const bf16x8*)(A_sc + ((size_t)ng * 64 + cb) * 128 + p * 8);
        float part = 0.f;
#pragma unroll
        for (int c = 0; c < 8; c++) part += hsh[nl * 8 + c] * (float)av[c];
        atomicAdd(Sn + ng * 16 + p, part);   // agent-scope, performed at LLC
      }
    }

    gridbar(bar, g0r, g0l);
    cur ^= 1;
  }
}

// ---------------- host ----------------
extern "C" void kernel_launch(void* const* d_in, const int* in_sizes, int n_in,
                              void* d_out, int out_size, void* d_ws, size_t ws_size,
                              hipStream_t stream) {
  const float* x     = (const float*)d_in[0];
  const float* A     = (const float*)d_in[1];
  const float* Wx    = (const float*)d_in[2];
  const float* Wh    = (const float*)d_in[3];
  const float* Wattn = (const float*)d_in[4];
  const float* bv    = (const float*)d_in[5];
  float* out = (float*)d_out;

  char* ws = (char*)d_ws;
  // ws layout (bytes) — sync state FIRST so array overflows can't corrupt it
  const size_t BAR_OFF = 0;          // 34*32*4 = 4352   (pad to 8192)
  const size_t S_OFF   = 8192;       // 3*2048*4        = 24576
  const size_t CB_OFF  = 32768;      // 128*512*4       = 262144
  const size_t ZB_OFF  = 294912;     // 2*131072*2      = 524288
  const size_t ASC_OFF = 819200;     // 128*8192*2      = 2097152
  const size_t WB_OFF  = 2916352;    // 64*32768*2      = 4194304
  const size_t BG_OFF  = 7110656;    // 128*64*32*16 el * 2B = 8388608
  const size_t WS_NEED = 15499264;   // BG_OFF + 8388608
  if (ws_size < WS_NEED) return;     // clean fail instead of corruption

  int*    bar  = (int*)(ws + BAR_OFF);
  float*  S    = (float*)(ws + S_OFF);
  float*  cbuf = (float*)(ws + CB_OFF);
  bf16_t* Zb   = (bf16_t*)(ws + ZB_OFF);
  bf16_t* A_sc = (bf16_t*)(ws + ASC_OFF);
  bf16_t* Wb   = (bf16_t*)(ws + WB_OFF);
  bf16_t* Bg   = (bf16_t*)(ws + BG_OFF);

  prepW_kernel<<<dim3(128), dim3(256), 0, stream>>>(Wh, Wx, Wb);
  prepA_kernel<<<dim3(128), dim3(256), 0, stream>>>(A, x, A_sc, cbuf, Zb, S, bar);
  prepB_kernel<<<dim3(512), dim3(256), 0, stream>>>(Wattn, A_sc, Bg);
  lstm_kernel<<<dim3(256), dim3(256), 0, stream>>>(x, A_sc, Wb, Bg, bv, cbuf, Zb, S, out, bar);
}

// Round 8
// 2700.845 us; speedup vs baseline: 5.4144x; 1.0148x over previous
//
#include <hip/hip_runtime.h>
#include <hip/hip_bf16.h>

typedef __bf16 bf16_t;
typedef __bf16 bf16x8 __attribute__((ext_vector_type(8)));
typedef float  f32x4  __attribute__((ext_vector_type(4)));

#define N_    128
#define T_    256
#define D_    512
#define H_    512
#define G4    2048
#define ZB_ELEMS 131072   /* 32kk*8nb*64*8 = 128x1024 fragment order */
#define WB_PER_CB 32768   /* 1024*32 */

// fragment-ordered index: k in [0,1024), n in [0,128)
__device__ __forceinline__ int zidx(int k, int n) {
  return ((((k >> 5) * 8 + (n >> 4)) * 64) + ((k >> 3) & 3) * 16 + (n & 15)) * 8 + (k & 7);
}

__device__ __forceinline__ float sigf(float x) { return 1.f / (1.f + __expf(-x)); }
__device__ __forceinline__ float tanhfast(float x) {
  float e = __expf(2.f * x);
  return 1.f - 2.f / (e + 1.f);
}

// ---- LLC-coherent access (agent-scope relaxed atomics -> sc1, no L2 wb/inv) ----
__device__ __forceinline__ bf16x8 ld_frag_llc(const bf16_t* p) {
  unsigned long long lo = __hip_atomic_load((const unsigned long long*)p,
      __ATOMIC_RELAXED, __HIP_MEMORY_SCOPE_AGENT);
  unsigned long long hi = __hip_atomic_load(((const unsigned long long*)p) + 1,
      __ATOMIC_RELAXED, __HIP_MEMORY_SCOPE_AGENT);
  union { unsigned long long q[2]; bf16x8 v; } u; u.q[0] = lo; u.q[1] = hi; return u.v;
}
__device__ __forceinline__ float ld_f32_llc(const float* p) {
  return __hip_atomic_load(p, __ATOMIC_RELAXED, __HIP_MEMORY_SCOPE_AGENT);
}
__device__ __forceinline__ void st_u32_llc(unsigned int* p, unsigned int v) {
  __hip_atomic_store(p, v, __ATOMIC_RELAXED, __HIP_MEMORY_SCOPE_AGENT);
}
__device__ __forceinline__ int ld_i32_llc(const int* p) {
  return __hip_atomic_load(p, __ATOMIC_RELAXED, __HIP_MEMORY_SCOPE_AGENT);
}
__device__ __forceinline__ unsigned int pack2bf(float lo, float hi) {
  union { bf16_t h[2]; unsigned int u; } q;
  q.h[0] = (bf16_t)lo; q.h[1] = (bf16_t)hi; return q.u;
}

// ---------------- prep: weights to fragment order (Wh rows 0..512, Wx 512..1024) --
__global__ void prepW_kernel(const float* __restrict__ Wh, const float* __restrict__ Wx,
                             bf16_t* __restrict__ Wb) {
  int cb = blockIdx.x >> 1, kq = blockIdx.x & 1;
  int tt = threadIdx.x;
  int hl = tt & 7, gate = (tt >> 3) & 3, ko = tt >> 5;
  int oc = gate * H_ + cb * 8 + hl;
  int jpl = hl * 4 + gate;
  int wcl = jpl >> 4, c = jpl & 15;
  for (int kb = kq * 64; kb < kq * 64 + 64; kb++) {
    int k = kb * 8 + ko;
    float v = (k < 512) ? Wh[(size_t)k * G4 + oc] : Wx[(size_t)(k - 512) * G4 + oc];
    int kk = k >> 5, ch = (k >> 3) & 3, e = k & 7;
    Wb[(size_t)cb * WB_PER_CB + (((kk * 2 + wcl) * 64) + ch * 16 + c) * 8 + e] = (bf16_t)v;
  }
}

// ---------------- prep: A_sc layout, h0/c0, Zb[0] h+x, S[0] scores, S[1]=0, bar ----
__global__ void prepA_kernel(const float* __restrict__ A, const float* __restrict__ x,
                             bf16_t* __restrict__ A_sc, float* __restrict__ cbuf,
                             bf16_t* __restrict__ Zb, float* __restrict__ S,
                             int* __restrict__ bar) {
  __shared__ float a_ld[8192];   // A[n]: [h][p] f32, 32KB
  __shared__ float h0s[512];
  __shared__ float redb[256 * 16];
  int n = blockIdx.x, tid = threadIdx.x;
  if (n == 0 && tid < 34) bar[tid * 32] = 0;   // leafctr[16], rootctr, gen_root, gen_leaf[16]
  if (tid < 16) S[2048 + n * 16 + tid] = 0.f;   // zero S[1]
  for (int i = tid; i < 8192; i += 256) a_ld[i] = A[(size_t)n * 8192 + i];
  __syncthreads();
  for (int h = tid; h < H_; h += 256) {
    float s = 0.f;
#pragma unroll
    for (int p = 0; p < 16; p++) s += a_ld[h * 16 + p];
    s *= (1.f / 16.f);
    h0s[h] = s;
    cbuf[n * H_ + h] = s;
    Zb[zidx(h, n)] = (bf16_t)s;
  }
  // x for t=0
  for (int d = tid; d < D_; d += 256)
    Zb[zidx(512 + d, n)] = (bf16_t)x[(size_t)n * T_ * D_ + d];
  // A_sc[n][cb][p][c] = A[n][cb*8+c][p]
  for (int idx = tid; idx < 8192; idx += 256) {
    int k = idx >> 4, p = idx & 15;
    A_sc[(size_t)n * 8192 + ((k >> 3) * 16 + p) * 8 + (k & 7)] = (bf16_t)a_ld[idx];
  }
  __syncthreads();
  // S[0][n][p] = sum_h h0[h]*A[n][h][p]  (raw, scale applied in softmax)
  float part[16];
#pragma unroll
  for (int p = 0; p < 16; p++) part[p] = 0.f;
  for (int h = tid; h < H_; h += 256) {
    float hv = h0s[h];
#pragma unroll
    for (int p = 0; p < 16; p++) part[p] += hv * a_ld[h * 16 + p];
  }
#pragma unroll
  for (int p = 0; p < 16; p++) redb[tid * 16 + p] = part[p];
  __syncthreads();
  if (tid < 16) {
    float s = 0.f;
    for (int i = 0; i < 256; i++) s += redb[i * 16 + tid];
    S[n * 16 + tid] = s;
  }
}

// ---------------- prep: B[n,p,j] = sum_h A[n,h,p]*Wattn[h,j], stored [n][cb][jl][p] --
__global__ void __launch_bounds__(256) prepB_kernel(const float* __restrict__ Wattn,
                             const bf16_t* __restrict__ A_sc, bf16_t* __restrict__ Bg) {
  __shared__ bf16_t Al[8192];   // [cb][p][c] = 1024 bf16x8 (FULLY staged — round-5 fix)
  int n = blockIdx.x >> 2, jpQ = blockIdx.x & 3;
  int tid = threadIdx.x, p = tid & 15, jg = tid >> 4;
  for (int i = tid; i < 1024; i += 256)
    ((bf16x8*)Al)[i] = ((const bf16x8*)(A_sc + (size_t)n * 8192))[i];
  __syncthreads();
  int cbb = jpQ * 16 + jg;
  float acc[32];
#pragma unroll
  for (int j = 0; j < 32; j++) acc[j] = 0.f;
  for (int k = 0; k < 512; k++) {
    float a = (float)Al[((k >> 3) * 16 + p) * 8 + (k & 7)];
    const float* wr = Wattn + (size_t)k * G4 + cbb * 8;
#pragma unroll
    for (int gate = 0; gate < 4; gate++) {
      const float4* w4 = (const float4*)(wr + gate * H_);
      float4 wa = w4[0], wb = w4[1];
      acc[0 * 4 + gate] += a * wa.x; acc[1 * 4 + gate] += a * wa.y;
      acc[2 * 4 + gate] += a * wa.z; acc[3 * 4 + gate] += a * wa.w;
      acc[4 * 4 + gate] += a * wb.x; acc[5 * 4 + gate] += a * wb.y;
      acc[6 * 4 + gate] += a * wb.z; acc[7 * 4 + gate] += a * wb.w;
    }
  }
  bf16_t* dst = Bg + (((size_t)n * 64 + cbb) * 32) * 16 + p;
#pragma unroll
  for (int jj = 0; jj < 32; jj++) dst[jj * 16] = (bf16_t)acc[jj];
}

// ---- fence-free 2-level barrier with tree wake (all relaxed; sc1 data path) ----
// g0r/g0l are this episode's epoch values, captured at STEP START (their loads
// complete via the step's intervening __syncthreads vmcnt drains).
__device__ __forceinline__ void gridbar(int* bar, int g0r, int g0l) {
  __syncthreads();   // vmcnt(0): all this block's sc1 stores are in LLC
  if (threadIdx.x == 0) {
    const int leaf = blockIdx.x >> 4;               // 16 leaves x 16 WGs
    int* leafctr  = bar + leaf * 32;
    int* rootctr  = bar + 16 * 32;
    int* gen_root = bar + 17 * 32;
    int* gen_leaf = bar + (18 + leaf) * 32;
    int my = __hip_atomic_fetch_add(leafctr, 1, __ATOMIC_RELAXED, __HIP_MEMORY_SCOPE_AGENT);
    if ((my & 15) == 15) {                          // leaf winner
      int r = __hip_atomic_fetch_add(rootctr, 1, __ATOMIC_RELAXED, __HIP_MEMORY_SCOPE_AGENT);
      if ((r & 15) == 15) {                         // root winner: flip epoch
        __hip_atomic_fetch_add(gen_root, 1, __ATOMIC_RELAXED, __HIP_MEMORY_SCOPE_AGENT);
      } else {
        while (ld_i32_llc(gen_root) == g0r) __builtin_amdgcn_s_sleep(2);
      }
      __hip_atomic_fetch_add(gen_leaf, 1, __ATOMIC_RELAXED, __HIP_MEMORY_SCOPE_AGENT);
    } else {
      while (ld_i32_llc(gen_leaf) == g0l) __builtin_amdgcn_s_sleep(2);
    }
  }
  __syncthreads();
}

// ---------------- persistent recurrent kernel --------------------------------
__global__ void __launch_bounds__(256, 2)
lstm_kernel(const float* __restrict__ x, const bf16_t* __restrict__ A_sc,
            const bf16_t* __restrict__ Wb, const bf16_t* __restrict__ Bg,
            const float* __restrict__ bvec, const float* __restrict__ cbuf,
            bf16_t* __restrict__ Zb, float* __restrict__ S,
            float* __restrict__ out, int* __restrict__ bar) {
  __shared__ bf16_t Wl[32768];        // 64KB [kk 0..31][wc][64][8]
  __shared__ float hsh[32 * 8];
  __shared__ float wls[32 * 16];

  const int wg = blockIdx.x, tid = threadIdx.x;
  const int cb = wg & 63, sbi = wg >> 6;
  const int wave = tid >> 6, lane = tid & 63;
  const int wr = wave >> 1, wc = wave & 1;
  const int nb = sbi * 2 + wr;
  const int s  = sbi * 32 + wr * 16 + (lane & 15);
  const int hc = cb * 8 + wc * 4 + (lane >> 4);
  const int jp = cb * 32 + wc * 16 + (lane & 15);
  const float bias_l = bvec[(jp & 3) * H_ + (jp >> 2)];
  const int jl = wc * 16 + (lane & 15);

  // one-time LDS staging: W slice only (64KB) -> 2 blocks/CU co-residency
  {
    const bf16x8* src = (const bf16x8*)(Wb + (size_t)cb * WB_PER_CB);
    bf16x8* dst = (bf16x8*)Wl;
    for (int i = tid; i < 4096; i += 256) dst[i] = src[i];
  }
  float creg = cbuf[s * H_ + hc];   // c lives in a register for all 256 steps
  __syncthreads();

  int cur = 0;
  for (int t = 0; t < T_; t++) {
    const bf16_t* Zc = Zb + cur * ZB_ELEMS;
    bf16_t* Zn = Zb + (cur ^ 1) * ZB_ELEMS;
    const int cur3 = t % 3, nxt3 = (t + 1) % 3, z3 = (t + 2) % 3;

    // capture this episode's epochs EARLY (completed by later syncthreads;
    // asm barrier pins them against sinking past the arrival fetch_add)
    int g0r = 0, g0l = 0;
    if (tid == 0) {
      g0r = ld_i32_llc(bar + 17 * 32);
      g0l = ld_i32_llc(bar + (18 + (wg >> 4)) * 32);
    }
    asm volatile("" ::: "memory");

    // zero my slice of S[(t+2)%3] (sc1 store, lands at LLC)
    if (tid < 8) st_u32_llc((unsigned int*)(S + z3 * 2048 + wg * 8 + tid), 0u);

    // stage x_{t+1} fragments into Zn (this WG's 8 K-rows, its 32 samples)
    if (t + 1 < T_ && tid < 128) {
      int nl = tid >> 2, e2 = (tid & 3) * 2;
      int n = sbi * 32 + nl;
      const float* xp = x + ((size_t)n * T_ + (t + 1)) * D_ + cb * 8 + e2;
      st_u32_llc((unsigned int*)(Zn + zidx(512 + cb * 8 + e2, n)), pack2bf(xp[0], xp[1]));
    }

    // softmax for my 32 samples (8 per wave, redundant across cb — cheap)
    if ((tid & 63) < 8) {
      int nl = wave * 8 + (tid & 63);
      int ng = sbi * 32 + nl;
      float r[16];
#pragma unroll
      for (int p = 0; p < 16; p++)
        r[p] = ld_f32_llc(S + cur3 * 2048 + ng * 16 + p) * 0.044194173824159216f;
      float m = r[0];
#pragma unroll
      for (int p = 1; p < 16; p++) m = fmaxf(m, r[p]);
      float ssum = 0.f;
#pragma unroll
      for (int p = 0; p < 16; p++) { r[p] = __expf(r[p] - m); ssum += r[p]; }
      float inv = 1.f / ssum;
#pragma unroll
      for (int p = 0; p < 16; p++) wls[nl * 16 + p] = r[p] * inv;
    }

    // GEMM: [h|x](32 samples x 1024) @ W(1024 x 32 cols); Z via sc1 (LLC-fresh)
    f32x4 acc = {0.f, 0.f, 0.f, 0.f};
    {
      const bf16x8* Wf = (const bf16x8*)Wl;
#pragma unroll 8
      for (int kk = 0; kk < 32; kk++) {
        bf16x8 a = ld_frag_llc(Zc + ((size_t)(kk * 8 + nb) * 64 + lane) * 8);
        bf16x8 b = Wf[(kk * 2 + wc) * 64 + lane];
        acc = __builtin_amdgcn_mfma_f32_16x16x32_bf16(a, b, acc, 0, 0, 0);
      }
    }
    __syncthreads();   // wls ready

    // + w@B + bias; Bg is read-only -> normal loads, L2 stays warm (no inv!)
    {
      const int nl0 = wr * 16 + ((lane >> 4) << 2);
#pragma unroll
      for (int rp = 0; rp < 4; rp++) {
        int nl = nl0 + rp;
        const bf16x8* bl = (const bf16x8*)(Bg +
            (((size_t)(sbi * 32 + nl) * 64 + cb) * 32 + jl) * 16);
        bf16x8 b0 = bl[0], b1 = bl[1];
        const float* wn = wls + nl * 16;
        float add = 0.f;
#pragma unroll
        for (int p = 0; p < 8; p++) add += wn[p] * (float)b0[p];
#pragma unroll
        for (int p = 0; p < 8; p++) add += wn[8 + p] * (float)b1[p];
        acc[rp] += add + bias_l;
      }
    }

    // gather i,f,o,g quads
    float gv[4] = {0.f, 0.f, 0.f, 0.f};
    const int srcbase = ((lane >> 2) & 3) * 16 + (lane >> 4) * 4;
#pragma unroll
    for (int rp = 0; rp < 4; rp++) {
      float v = acc[rp];
#pragma unroll
      for (int g = 0; g < 4; g++) {
        float sv = __shfl(v, srcbase + g, 64);
        if ((lane & 3) == rp) gv[g] = sv;
      }
    }

    // gates, state update, outputs
    float si = sigf(gv[0]), sf = sigf(gv[1]), so = sigf(gv[2]);
    float cn = sf * creg + si * tanhfast(gv[3]);
    float hn = so * tanhfast(cn);
    creg = cn;
    __builtin_nontemporal_store(hn, out + ((size_t)s * T_ + t) * H_ + hc);

    // h_{t+1} to Zn (paired bf16 -> u32 sc1 store)
    {
      union { bf16_t h; unsigned short u; } cvt; cvt.h = (bf16_t)hn;
      unsigned int hbits = cvt.u;
      unsigned int other = __shfl(hbits, (lane + 16) & 63, 64);
      if (((lane >> 4) & 1) == 0)
        st_u32_llc((unsigned int*)(Zn + zidx(hc, s)), hbits | (other << 16));
    }
    hsh[(s & 31) * 8 + (hc & 7)] = hn;
    __syncthreads();   // hsh ready

    // partial scores for t+1: my 8 h-cols x my 32 samples (A_sc read-only, L2-warm)
    if (t + 1 < T_) {
      float* Sn = S + nxt3 * 2048;
#pragma unroll
      for (int u = 0; u < 2; u++) {
        int idx = tid + u * 256;
        int nl = idx >> 4, p = idx & 15;
        int ng = sbi * 32 + nl;
        const bf16x8 av = *(const bf16x8*)(A_sc + ((size_t)ng * 64 + cb) * 128 + p * 8);
        float part = 0.f;
#pragma unroll
        for (int c = 0; c < 8; c++) part += hsh[nl * 8 + c] * (float)av[c];
        atomicAdd(Sn + ng * 16 + p, part);   // agent-scope, performed at LLC
      }
    }

    gridbar(bar, g0r, g0l);
    cur ^= 1;
  }
}

// ---------------- host ----------------
extern "C" void kernel_launch(void* const* d_in, const int* in_sizes, int n_in,
                              void* d_out, int out_size, void* d_ws, size_t ws_size,
                              hipStream_t stream) {
  const float* x     = (const float*)d_in[0];
  const float* A     = (const float*)d_in[1];
  const float* Wx    = (const float*)d_in[2];
  const float* Wh    = (const float*)d_in[3];
  const float* Wattn = (const float*)d_in[4];
  const float* bv    = (const float*)d_in[5];
  float* out = (float*)d_out;

  char* ws = (char*)d_ws;
  // ws layout (bytes) — sync state FIRST so array overflows can't corrupt it
  const size_t BAR_OFF = 0;          // 34*32*4 = 4352   (pad to 8192)
  const size_t S_OFF   = 8192;       // 3*2048*4        = 24576
  const size_t CB_OFF  = 32768;      // 128*512*4       = 262144
  const size_t ZB_OFF  = 294912;     // 2*131072*2      = 524288
  const size_t ASC_OFF = 819200;     // 128*8192*2      = 2097152
  const size_t WB_OFF  = 2916352;    // 64*32768*2      = 4194304
  const size_t BG_OFF  = 7110656;    // 128*64*32*16 el * 2B = 8388608
  const size_t WS_NEED = 15499264;   // BG_OFF + 8388608
  if (ws_size < WS_NEED) return;     // clean fail instead of corruption

  int*    bar  = (int*)(ws + BAR_OFF);
  float*  S    = (float*)(ws + S_OFF);
  float*  cbuf = (float*)(ws + CB_OFF);
  bf16_t* Zb   = (bf16_t*)(ws + ZB_OFF);
  bf16_t* A_sc = (bf16_t*)(ws + ASC_OFF);
  bf16_t* Wb   = (bf16_t*)(ws + WB_OFF);
  bf16_t* Bg   = (bf16_t*)(ws + BG_OFF);

  prepW_kernel<<<dim3(128), dim3(256), 0, stream>>>(Wh, Wx, Wb);
  prepA_kernel<<<dim3(128), dim3(256), 0, stream>>>(A, x, A_sc, cbuf, Zb, S, bar);
  prepB_kernel<<<dim3(512), dim3(256), 0, stream>>>(Wattn, A_sc, Bg);
  lstm_kernel<<<dim3(256), dim3(256), 0, stream>>>(x, A_sc, Wb, Bg, bv, cbuf, Zb, S, out, bar);
}

// Round 9
// 2285.509 us; speedup vs baseline: 6.3983x; 1.1817x over previous
//
#include <hip/hip_runtime.h>
#include <hip/hip_bf16.h>

typedef __bf16 bf16_t;
typedef __bf16 bf16x8 __attribute__((ext_vector_type(8)));
typedef float  f32x4  __attribute__((ext_vector_type(4)));

#define N_    128
#define T_    256
#define D_    512
#define H_    512
#define G4    2048
#define ZB_ELEMS 131072   /* 32kk*8nb*64*8 = 128x1024 fragment order */
#define WB_PER_CB 32768   /* 1024*32 */

// fragment-ordered index: k in [0,1024), n in [0,128)
__device__ __forceinline__ int zidx(int k, int n) {
  return ((((k >> 5) * 8 + (n >> 4)) * 64) + ((k >> 3) & 3) * 16 + (n & 15)) * 8 + (k & 7);
}

__device__ __forceinline__ float sigf(float x) { return 1.f / (1.f + __expf(-x)); }
__device__ __forceinline__ float tanhfast(float x) {
  float e = __expf(2.f * x);
  return 1.f - 2.f / (e + 1.f);
}

// ---- LLC-coherent access (agent-scope relaxed atomics -> sc1, no L2 wb/inv) ----
__device__ __forceinline__ bf16x8 ld_frag_llc(const bf16_t* p) {
  unsigned long long lo = __hip_atomic_load((const unsigned long long*)p,
      __ATOMIC_RELAXED, __HIP_MEMORY_SCOPE_AGENT);
  unsigned long long hi = __hip_atomic_load(((const unsigned long long*)p) + 1,
      __ATOMIC_RELAXED, __HIP_MEMORY_SCOPE_AGENT);
  union { unsigned long long q[2]; bf16x8 v; } u; u.q[0] = lo; u.q[1] = hi; return u.v;
}
__device__ __forceinline__ float ld_f32_llc(const float* p) {
  return __hip_atomic_load(p, __ATOMIC_RELAXED, __HIP_MEMORY_SCOPE_AGENT);
}
__device__ __forceinline__ void st_u32_llc(unsigned int* p, unsigned int v) {
  __hip_atomic_store(p, v, __ATOMIC_RELAXED, __HIP_MEMORY_SCOPE_AGENT);
}
__device__ __forceinline__ int ld_i32_llc(const int* p) {
  return __hip_atomic_load(p, __ATOMIC_RELAXED, __HIP_MEMORY_SCOPE_AGENT);
}
__device__ __forceinline__ unsigned int pack2bf(float lo, float hi) {
  union { bf16_t h[2]; unsigned int u; } q;
  q.h[0] = (bf16_t)lo; q.h[1] = (bf16_t)hi; return q.u;
}

// ---------------- prep: weights to fragment order (Wh rows 0..512, Wx 512..1024) --
__global__ void prepW_kernel(const float* __restrict__ Wh, const float* __restrict__ Wx,
                             bf16_t* __restrict__ Wb) {
  int cb = blockIdx.x >> 1, kq = blockIdx.x & 1;
  int tt = threadIdx.x;
  int hl = tt & 7, gate = (tt >> 3) & 3, ko = tt >> 5;
  int oc = gate * H_ + cb * 8 + hl;
  int jpl = hl * 4 + gate;
  int wcl = jpl >> 4, c = jpl & 15;
  for (int kb = kq * 64; kb < kq * 64 + 64; kb++) {
    int k = kb * 8 + ko;
    float v = (k < 512) ? Wh[(size_t)k * G4 + oc] : Wx[(size_t)(k - 512) * G4 + oc];
    int kk = k >> 5, ch = (k >> 3) & 3, e = k & 7;
    Wb[(size_t)cb * WB_PER_CB + (((kk * 2 + wcl) * 64) + ch * 16 + c) * 8 + e] = (bf16_t)v;
  }
}

// ---------------- prep: A_sc layout, h0/c0, Zb[0] h+x, S[0] scores, S[1]=0, bar ----
__global__ void prepA_kernel(const float* __restrict__ A, const float* __restrict__ x,
                             bf16_t* __restrict__ A_sc, float* __restrict__ cbuf,
                             bf16_t* __restrict__ Zb, float* __restrict__ S,
                             int* __restrict__ bar) {
  __shared__ float a_ld[8192];   // A[n]: [h][p] f32, 32KB
  __shared__ float h0s[512];
  __shared__ float redb[256 * 16];
  int n = blockIdx.x, tid = threadIdx.x;
  if (n == 0 && tid < 144) bar[tid * 32] = 0;   // 8 groups x 18 lines
  if (tid < 16) S[2048 + n * 16 + tid] = 0.f;   // zero S[1]
  for (int i = tid; i < 8192; i += 256) a_ld[i] = A[(size_t)n * 8192 + i];
  __syncthreads();
  for (int h = tid; h < H_; h += 256) {
    float s = 0.f;
#pragma unroll
    for (int p = 0; p < 16; p++) s += a_ld[h * 16 + p];
    s *= (1.f / 16.f);
    h0s[h] = s;
    cbuf[n * H_ + h] = s;
    Zb[zidx(h, n)] = (bf16_t)s;
  }
  // x for t=0
  for (int d = tid; d < D_; d += 256)
    Zb[zidx(512 + d, n)] = (bf16_t)x[(size_t)n * T_ * D_ + d];
  // A_sc[n][cb][p][c] = A[n][cb*8+c][p]
  for (int idx = tid; idx < 8192; idx += 256) {
    int k = idx >> 4, p = idx & 15;
    A_sc[(size_t)n * 8192 + ((k >> 3) * 16 + p) * 8 + (k & 7)] = (bf16_t)a_ld[idx];
  }
  __syncthreads();
  // S[0][n][p] = sum_h h0[h]*A[n][h][p]  (raw, scale applied in softmax)
  float part[16];
#pragma unroll
  for (int p = 0; p < 16; p++) part[p] = 0.f;
  for (int h = tid; h < H_; h += 256) {
    float hv = h0s[h];
#pragma unroll
    for (int p = 0; p < 16; p++) part[p] += hv * a_ld[h * 16 + p];
  }
#pragma unroll
  for (int p = 0; p < 16; p++) redb[tid * 16 + p] = part[p];
  __syncthreads();
  if (tid < 16) {
    float s = 0.f;
    for (int i = 0; i < 256; i++) s += redb[i * 16 + tid];
    S[n * 16 + tid] = s;
  }
}

// ---------------- prep: B[n,p,j] = sum_h A[n,h,p]*Wattn[h,j], stored [n][cb][jl][p] --
__global__ void __launch_bounds__(256) prepB_kernel(const float* __restrict__ Wattn,
                             const bf16_t* __restrict__ A_sc, bf16_t* __restrict__ Bg) {
  __shared__ bf16_t Al[8192];   // [cb][p][c] = 1024 bf16x8 (FULLY staged)
  int n = blockIdx.x >> 2, jpQ = blockIdx.x & 3;
  int tid = threadIdx.x, p = tid & 15, jg = tid >> 4;
  for (int i = tid; i < 1024; i += 256)
    ((bf16x8*)Al)[i] = ((const bf16x8*)(A_sc + (size_t)n * 8192))[i];
  __syncthreads();
  int cbb = jpQ * 16 + jg;
  float acc[32];
#pragma unroll
  for (int j = 0; j < 32; j++) acc[j] = 0.f;
  for (int k = 0; k < 512; k++) {
    float a = (float)Al[((k >> 3) * 16 + p) * 8 + (k & 7)];
    const float* wr = Wattn + (size_t)k * G4 + cbb * 8;
#pragma unroll
    for (int gate = 0; gate < 4; gate++) {
      const float4* w4 = (const float4*)(wr + gate * H_);
      float4 wa = w4[0], wb = w4[1];
      acc[0 * 4 + gate] += a * wa.x; acc[1 * 4 + gate] += a * wa.y;
      acc[2 * 4 + gate] += a * wa.z; acc[3 * 4 + gate] += a * wa.w;
      acc[4 * 4 + gate] += a * wb.x; acc[5 * 4 + gate] += a * wb.y;
      acc[6 * 4 + gate] += a * wb.z; acc[7 * 4 + gate] += a * wb.w;
    }
  }
  bf16_t* dst = Bg + (((size_t)n * 64 + cbb) * 32) * 16 + p;
#pragma unroll
  for (int jj = 0; jj < 32; jj++) dst[jj * 16] = (bf16_t)acc[jj];
}

// ---- per-group fence-free barrier, 64 WGs, 8x8 tree (all relaxed / sc1) ----
// gbase layout (x32 ints): leafctr[0..7], rootctr(8), gen_root(9), gen_leaf[10..17]
__device__ __forceinline__ void gridbar(int* gbase, int leaf, int g0r, int g0l) {
  __syncthreads();   // vmcnt(0): all this block's sc1 stores are in LLC
  if (threadIdx.x == 0) {
    int* leafctr  = gbase + leaf * 32;
    int* rootctr  = gbase + 8 * 32;
    int* gen_root = gbase + 9 * 32;
    int* gen_leaf = gbase + (10 + leaf) * 32;
    int my = __hip_atomic_fetch_add(leafctr, 1, __ATOMIC_RELAXED, __HIP_MEMORY_SCOPE_AGENT);
    if ((my & 7) == 7) {                          // leaf winner
      int r = __hip_atomic_fetch_add(rootctr, 1, __ATOMIC_RELAXED, __HIP_MEMORY_SCOPE_AGENT);
      if ((r & 7) == 7) {                         // root winner: flip epoch
        __hip_atomic_fetch_add(gen_root, 1, __ATOMIC_RELAXED, __HIP_MEMORY_SCOPE_AGENT);
      } else {
        while (ld_i32_llc(gen_root) == g0r) __builtin_amdgcn_s_sleep(2);
      }
      __hip_atomic_fetch_add(gen_leaf, 1, __ATOMIC_RELAXED, __HIP_MEMORY_SCOPE_AGENT);
    } else {
      while (ld_i32_llc(gen_leaf) == g0l) __builtin_amdgcn_s_sleep(2);
    }
  }
  __syncthreads();
}

// ---------------- persistent recurrent kernel --------------------------------
// 512 WGs = 8 groups(16 samples) x 64 col-blocks; 2 blocks/CU co-resident so
// independent groups hide each other's barrier latency.
__global__ void __launch_bounds__(256, 2)
lstm_kernel(const float* __restrict__ x, const bf16_t* __restrict__ A_sc,
            const bf16_t* __restrict__ Wb, const bf16_t* __restrict__ Bg,
            const float* __restrict__ bvec, const float* __restrict__ cbuf,
            bf16_t* __restrict__ Zb, float* __restrict__ S,
            float* __restrict__ out, int* __restrict__ bar) {
  __shared__ bf16_t Wl[32768];        // 64KB [kk 0..31][wc][64][8]
  __shared__ f32x4 red[2][64];        // 2KB K-split partials
  __shared__ float hsh[16 * 9];       // padded rows (bank-conflict fix)
  __shared__ float wls[16 * 17];      // padded rows

  const int wg = blockIdx.x, tid = threadIdx.x;
  const int cb = wg & 63, grp = wg >> 6;
  const int wave = tid >> 6, lane = tid & 63;
  const int wc = wave & 1, kh = wave >> 1;      // col-half, K-half
  const int nb = grp;                           // 16-sample fragment row-block
  const int s  = grp * 16 + (lane & 15);        // epilogue sample (kh==0)
  const int hc = cb * 8 + wc * 4 + (lane >> 4);
  const int jp = cb * 32 + wc * 16 + (lane & 15);
  const float bias_l = bvec[(jp & 3) * H_ + (jp >> 2)];
  const int jl = wc * 16 + (lane & 15);
  const int leaf = cb >> 3;
  int* gbase = bar + grp * 18 * 32;

  // one-time LDS staging: W slice (64KB)
  {
    const bf16x8* src = (const bf16x8*)(Wb + (size_t)cb * WB_PER_CB);
    bf16x8* dst = (bf16x8*)Wl;
    for (int i = tid; i < 4096; i += 256) dst[i] = src[i];
  }
  float creg = cbuf[s * H_ + hc];   // c in register for all 256 steps (kh==0 lanes)
  __syncthreads();

  int cur = 0;
  for (int t = 0; t < T_; t++) {
    const bf16_t* Zc = Zb + cur * ZB_ELEMS;
    bf16_t* Zn = Zb + (cur ^ 1) * ZB_ELEMS;
    const int cur3 = t % 3, nxt3 = (t + 1) % 3, z3 = (t + 2) % 3;

    // capture this episode's epochs EARLY (proved: exactly t at this point)
    int g0r = 0, g0l = 0;
    if (tid == 0) {
      g0r = ld_i32_llc(gbase + 9 * 32);
      g0l = ld_i32_llc(gbase + (10 + leaf) * 32);
    }
    asm volatile("" ::: "memory");

    // zero group's S[(t+2)%3] slice: 4 floats per WG
    if (tid < 4) st_u32_llc((unsigned int*)(S + z3 * 2048 + grp * 256 + cb * 4 + tid), 0u);

    // stage x_{t+1}: this WG's 8 K-rows x its 16 samples
    if (t + 1 < T_ && tid < 64) {
      int nl = tid >> 2, e2 = (tid & 3) * 2;
      int n = grp * 16 + nl;
      const float* xp = x + ((size_t)n * T_ + (t + 1)) * D_ + cb * 8 + e2;
      st_u32_llc((unsigned int*)(Zn + zidx(512 + cb * 8 + e2, n)), pack2bf(xp[0], xp[1]));
    }

    // softmax: 16 lanes (4 per wave), one sample each
    if ((tid & 63) < 4) {
      int nl = wave * 4 + (tid & 63);
      int ng = grp * 16 + nl;
      float r[16];
#pragma unroll
      for (int p = 0; p < 16; p++)
        r[p] = ld_f32_llc(S + cur3 * 2048 + ng * 16 + p) * 0.044194173824159216f;
      float m = r[0];
#pragma unroll
      for (int p = 1; p < 16; p++) m = fmaxf(m, r[p]);
      float ssum = 0.f;
#pragma unroll
      for (int p = 0; p < 16; p++) { r[p] = __expf(r[p] - m); ssum += r[p]; }
      float inv = 1.f / ssum;
#pragma unroll
      for (int p = 0; p < 16; p++) wls[nl * 17 + p] = r[p] * inv;
    }

    // GEMM K-half: [h|x](16 samples x 512) @ W(512 x 32 cols)
    f32x4 acc = {0.f, 0.f, 0.f, 0.f};
    {
      const bf16x8* Wf = (const bf16x8*)Wl;
#pragma unroll 8
      for (int i = 0; i < 16; i++) {
        int kk = kh * 16 + i;
        bf16x8 a = ld_frag_llc(Zc + ((size_t)(kk * 8 + nb) * 64 + lane) * 8);
        bf16x8 b = Wf[(kk * 2 + wc) * 64 + lane];
        acc = __builtin_amdgcn_mfma_f32_16x16x32_bf16(a, b, acc, 0, 0, 0);
      }
    }
    if (kh == 1) red[wc][lane] = acc;
    __syncthreads();   // red + wls ready

    if (kh == 0) {
      {
        f32x4 o = red[wc][lane];
        acc[0] += o[0]; acc[1] += o[1]; acc[2] += o[2]; acc[3] += o[3];
      }
      // + w@B + bias (acc row rp = sample (lane>>4)*4+rp); Bg L2-warm
      const int nl0 = (lane >> 4) << 2;
#pragma unroll
      for (int rp = 0; rp < 4; rp++) {
        int nl = nl0 + rp;
        const bf16x8* bl = (const bf16x8*)(Bg +
            (((size_t)(grp * 16 + nl) * 64 + cb) * 32 + jl) * 16);
        bf16x8 b0 = bl[0], b1 = bl[1];
        const float* wn = wls + nl * 17;
        float add = 0.f;
#pragma unroll
        for (int p = 0; p < 8; p++) add += wn[p] * (float)b0[p];
#pragma unroll
        for (int p = 0; p < 8; p++) add += wn[8 + p] * (float)b1[p];
        acc[rp] += add + bias_l;
      }

      // gather i,f,o,g quads (within-wave shuffle)
      float gv[4] = {0.f, 0.f, 0.f, 0.f};
      const int srcbase = ((lane >> 2) & 3) * 16 + (lane >> 4) * 4;
#pragma unroll
      for (int rp = 0; rp < 4; rp++) {
        float v = acc[rp];
#pragma unroll
        for (int g = 0; g < 4; g++) {
          float sv = __shfl(v, srcbase + g, 64);
          if ((lane & 3) == rp) gv[g] = sv;
        }
      }

      // gates, state update, outputs
      float si = sigf(gv[0]), sf = sigf(gv[1]), so = sigf(gv[2]);
      float cn = sf * creg + si * tanhfast(gv[3]);
      float hn = so * tanhfast(cn);
      creg = cn;
      __builtin_nontemporal_store(hn, out + ((size_t)s * T_ + t) * H_ + hc);

      // h_{t+1} to Zn (paired bf16 -> u32 sc1 store)
      union { bf16_t h; unsigned short u; } cvt; cvt.h = (bf16_t)hn;
      unsigned int hbits = cvt.u;
      unsigned int other = __shfl(hbits, (lane + 16) & 63, 64);
      if (((lane >> 4) & 1) == 0)
        st_u32_llc((unsigned int*)(Zn + zidx(hc, s)), hbits | (other << 16));
      hsh[(s & 15) * 9 + (hc & 7)] = hn;
    }
    __syncthreads();   // hsh ready

    // partial scores for t+1: 256 threads, one (sample,p) each, dot over 8 hc
    if (t + 1 < T_) {
      int nl = tid >> 4, p = tid & 15;
      int ng = grp * 16 + nl;
      const bf16x8 av = *(const bf16x8*)(A_sc + ((size_t)ng * 64 + cb) * 128 + p * 8);
      float part = 0.f;
#pragma unroll
      for (int c = 0; c < 8; c++) part += hsh[nl * 9 + c] * (float)av[c];
      atomicAdd(S + nxt3 * 2048 + ng * 16 + p, part);   // agent-scope, at LLC
    }

    gridbar(gbase, leaf, g0r, g0l);
    cur ^= 1;
  }
}

// ---------------- host ----------------
extern "C" void kernel_launch(void* const* d_in, const int* in_sizes, int n_in,
                              void* d_out, int out_size, void* d_ws, size_t ws_size,
                              hipStream_t stream) {
  const float* x     = (const float*)d_in[0];
  const float* A     = (const float*)d_in[1];
  const float* Wx    = (const float*)d_in[2];
  const float* Wh    = (const float*)d_in[3];
  const float* Wattn = (const float*)d_in[4];
  const float* bv    = (const float*)d_in[5];
  float* out = (float*)d_out;

  char* ws = (char*)d_ws;
  // ws layout (bytes) — sync state FIRST so array overflows can't corrupt it
  const size_t BAR_OFF = 0;          // 8 grp * 18 lines * 128B = 18432 (pad 32768)
  const size_t S_OFF   = 32768;      // 3*2048*4        = 24576
  const size_t CB_OFF  = 57344;      // 128*512*4       = 262144
  const size_t ZB_OFF  = 319488;     // 2*131072*2      = 524288
  const size_t ASC_OFF = 843776;     // 128*8192*2      = 2097152
  const size_t WB_OFF  = 2940928;    // 64*32768*2      = 4194304
  const size_t BG_OFF  = 7135232;    // 128*64*32*16 el * 2B = 8388608
  const size_t WS_NEED = 15523840;   // BG_OFF + 8388608
  if (ws_size < WS_NEED) return;     // clean fail instead of corruption

  int*    bar  = (int*)(ws + BAR_OFF);
  float*  S    = (float*)(ws + S_OFF);
  float*  cbuf = (float*)(ws + CB_OFF);
  bf16_t* Zb   = (bf16_t*)(ws + ZB_OFF);
  bf16_t* A_sc = (bf16_t*)(ws + ASC_OFF);
  bf16_t* Wb   = (bf16_t*)(ws + WB_OFF);
  bf16_t* Bg   = (bf16_t*)(ws + BG_OFF);

  prepW_kernel<<<dim3(128), dim3(256), 0, stream>>>(Wh, Wx, Wb);
  prepA_kernel<<<dim3(128), dim3(256), 0, stream>>>(A, x, A_sc, cbuf, Zb, S, bar);
  prepB_kernel<<<dim3(512), dim3(256), 0, stream>>>(Wattn, A_sc, Bg);
  lstm_kernel<<<dim3(512), dim3(256), 0, stream>>>(x, A_sc, Wb, Bg, bv, cbuf, Zb, S, out, bar);
}

// Round 10
// 1945.915 us; speedup vs baseline: 7.5149x; 1.1745x over previous
//
#include <hip/hip_runtime.h>
#include <hip/hip_bf16.h>

typedef __bf16 bf16_t;
typedef __bf16 bf16x8 __attribute__((ext_vector_type(8)));
typedef float  f32x4  __attribute__((ext_vector_type(4)));

#define N_    128
#define T_    256
#define D_    512
#define H_    512
#define G4    2048
#define ZB_ELEMS 131072   /* full-K Z buffer: 32kk*8nb*64*8 (x half unused in Xf mode) */
#define XF_PER_T 65536    /* 16kk*8nb*64*8 = 128x512 x-fragments per step */
#define WB_PER_CB 32768   /* 1024*32 */

// fragment-ordered index: k in [0,1024), n in [0,128)
__device__ __forceinline__ int zidx(int k, int n) {
  return ((((k >> 5) * 8 + (n >> 4)) * 64) + ((k >> 3) & 3) * 16 + (n & 15)) * 8 + (k & 7);
}

__device__ __forceinline__ float sigf(float x) { return 1.f / (1.f + __expf(-x)); }
__device__ __forceinline__ float tanhfast(float x) {
  float e = __expf(2.f * x);
  return 1.f - 2.f / (e + 1.f);
}

// ---- LLC-coherent access (agent-scope relaxed atomics -> sc1, no L2 wb/inv) ----
__device__ __forceinline__ bf16x8 ld_frag_llc(const bf16_t* p) {
  unsigned long long lo = __hip_atomic_load((const unsigned long long*)p,
      __ATOMIC_RELAXED, __HIP_MEMORY_SCOPE_AGENT);
  unsigned long long hi = __hip_atomic_load(((const unsigned long long*)p) + 1,
      __ATOMIC_RELAXED, __HIP_MEMORY_SCOPE_AGENT);
  union { unsigned long long q[2]; bf16x8 v; } u; u.q[0] = lo; u.q[1] = hi; return u.v;
}
__device__ __forceinline__ float ld_f32_llc(const float* p) {
  return __hip_atomic_load(p, __ATOMIC_RELAXED, __HIP_MEMORY_SCOPE_AGENT);
}
__device__ __forceinline__ void st_u32_llc(unsigned int* p, unsigned int v) {
  __hip_atomic_store(p, v, __ATOMIC_RELAXED, __HIP_MEMORY_SCOPE_AGENT);
}
__device__ __forceinline__ int ld_i32_llc(const int* p) {
  return __hip_atomic_load(p, __ATOMIC_RELAXED, __HIP_MEMORY_SCOPE_AGENT);
}
__device__ __forceinline__ unsigned int pack2bf(float lo, float hi) {
  union { bf16_t h[2]; unsigned int u; } q;
  q.h[0] = (bf16_t)lo; q.h[1] = (bf16_t)hi; return q.u;
}

// ---------------- prep: weights to fragment order (Wh rows 0..512, Wx 512..1024) --
__global__ void prepW_kernel(const float* __restrict__ Wh, const float* __restrict__ Wx,
                             bf16_t* __restrict__ Wb) {
  int cb = blockIdx.x >> 1, kq = blockIdx.x & 1;
  int tt = threadIdx.x;
  int hl = tt & 7, gate = (tt >> 3) & 3, ko = tt >> 5;
  int oc = gate * H_ + cb * 8 + hl;
  int jpl = hl * 4 + gate;
  int wcl = jpl >> 4, c = jpl & 15;
  for (int kb = kq * 64; kb < kq * 64 + 64; kb++) {
    int k = kb * 8 + ko;
    float v = (k < 512) ? Wh[(size_t)k * G4 + oc] : Wx[(size_t)(k - 512) * G4 + oc];
    int kk = k >> 5, ch = (k >> 3) & 3, e = k & 7;
    Wb[(size_t)cb * WB_PER_CB + (((kk * 2 + wcl) * 64) + ch * 16 + c) * 8 + e] = (bf16_t)v;
  }
}

// ---------------- prep: x fragments for ALL steps (read-only in loop) -----------
__global__ void prepX_kernel(const float* __restrict__ x, bf16_t* __restrict__ Xf) {
  int gid = blockIdx.x * 256 + threadIdx.x;   // 8192 blocks
  int e8 = gid & 63;                          // k = e8*8 .. +7
  int n  = (gid >> 6) & 127;
  int t  = gid >> 13;
  int k  = e8 * 8;
  const float* xp = x + ((size_t)n * T_ + t) * D_ + k;
  union { bf16_t b[8]; bf16x8 v; } u;
#pragma unroll
  for (int e = 0; e < 8; e++) u.b[e] = (bf16_t)xp[e];
  int idx = ((k >> 5) * 8 + (n >> 4)) * 64 + ((k >> 3) & 3) * 16 + (n & 15);
  ((bf16x8*)(Xf + (size_t)t * XF_PER_T))[idx] = u.v;
}

// ---------------- prep: A_sc layout, h0/c0, Zb[0] h+x, S[0] scores, S[1]=0, bar ----
__global__ void prepA_kernel(const float* __restrict__ A, const float* __restrict__ x,
                             bf16_t* __restrict__ A_sc, float* __restrict__ cbuf,
                             bf16_t* __restrict__ Zb, float* __restrict__ S,
                             int* __restrict__ bar) {
  __shared__ float a_ld[8192];   // A[n]: [h][p] f32, 32KB
  __shared__ float h0s[512];
  __shared__ float redb[256 * 16];
  int n = blockIdx.x, tid = threadIdx.x;
  if (n == 0 && tid < 144) bar[tid * 32] = 0;   // 8 groups x 18 lines
  if (tid < 16) S[2048 + n * 16 + tid] = 0.f;   // zero S[1]
  for (int i = tid; i < 8192; i += 256) a_ld[i] = A[(size_t)n * 8192 + i];
  __syncthreads();
  for (int h = tid; h < H_; h += 256) {
    float s = 0.f;
#pragma unroll
    for (int p = 0; p < 16; p++) s += a_ld[h * 16 + p];
    s *= (1.f / 16.f);
    h0s[h] = s;
    cbuf[n * H_ + h] = s;
    Zb[zidx(h, n)] = (bf16_t)s;
  }
  // x for t=0 (used only by the non-Xf fallback path; cheap, unconditional)
  for (int d = tid; d < D_; d += 256)
    Zb[zidx(512 + d, n)] = (bf16_t)x[(size_t)n * T_ * D_ + d];
  // A_sc[n][cb][p][c] = A[n][cb*8+c][p]
  for (int idx = tid; idx < 8192; idx += 256) {
    int k = idx >> 4, p = idx & 15;
    A_sc[(size_t)n * 8192 + ((k >> 3) * 16 + p) * 8 + (k & 7)] = (bf16_t)a_ld[idx];
  }
  __syncthreads();
  // S[0][n][p] = sum_h h0[h]*A[n][h][p]  (raw, scale applied in softmax)
  float part[16];
#pragma unroll
  for (int p = 0; p < 16; p++) part[p] = 0.f;
  for (int h = tid; h < H_; h += 256) {
    float hv = h0s[h];
#pragma unroll
    for (int p = 0; p < 16; p++) part[p] += hv * a_ld[h * 16 + p];
  }
#pragma unroll
  for (int p = 0; p < 16; p++) redb[tid * 16 + p] = part[p];
  __syncthreads();
  if (tid < 16) {
    float s = 0.f;
    for (int i = 0; i < 256; i++) s += redb[i * 16 + tid];
    S[n * 16 + tid] = s;
  }
}

// ---------------- prep: B[n,p,j] = sum_h A[n,h,p]*Wattn[h,j], stored [n][cb][jl][p] --
__global__ void __launch_bounds__(256) prepB_kernel(const float* __restrict__ Wattn,
                             const bf16_t* __restrict__ A_sc, bf16_t* __restrict__ Bg) {
  __shared__ bf16_t Al[8192];   // [cb][p][c] = 1024 bf16x8 (FULLY staged)
  int n = blockIdx.x >> 2, jpQ = blockIdx.x & 3;
  int tid = threadIdx.x, p = tid & 15, jg = tid >> 4;
  for (int i = tid; i < 1024; i += 256)
    ((bf16x8*)Al)[i] = ((const bf16x8*)(A_sc + (size_t)n * 8192))[i];
  __syncthreads();
  int cbb = jpQ * 16 + jg;
  float acc[32];
#pragma unroll
  for (int j = 0; j < 32; j++) acc[j] = 0.f;
  for (int k = 0; k < 512; k++) {
    float a = (float)Al[((k >> 3) * 16 + p) * 8 + (k & 7)];
    const float* wr = Wattn + (size_t)k * G4 + cbb * 8;
#pragma unroll
    for (int gate = 0; gate < 4; gate++) {
      const float4* w4 = (const float4*)(wr + gate * H_);
      float4 wa = w4[0], wb = w4[1];
      acc[0 * 4 + gate] += a * wa.x; acc[1 * 4 + gate] += a * wa.y;
      acc[2 * 4 + gate] += a * wa.z; acc[3 * 4 + gate] += a * wa.w;
      acc[4 * 4 + gate] += a * wb.x; acc[5 * 4 + gate] += a * wb.y;
      acc[6 * 4 + gate] += a * wb.z; acc[7 * 4 + gate] += a * wb.w;
    }
  }
  bf16_t* dst = Bg + (((size_t)n * 64 + cbb) * 32) * 16 + p;
#pragma unroll
  for (int jj = 0; jj < 32; jj++) dst[jj * 16] = (bf16_t)acc[jj];
}

// ---- per-group fence-free barrier, 64 WGs, 8x8 tree, DIRECT root broadcast ----
// gbase lines (x32 ints): leafctr[0..7], rootctr(8), gen_leaf[9..16]
__device__ __forceinline__ void gridbar(int* gbase, int leaf, int g0l) {
  __syncthreads();   // vmcnt(0): all this block's sc1 stores are in LLC
  if (threadIdx.x == 0) {
    int my = __hip_atomic_fetch_add(gbase + leaf * 32, 1, __ATOMIC_RELAXED, __HIP_MEMORY_SCOPE_AGENT);
    bool rootwin = false;
    if ((my & 7) == 7) {                          // leaf winner
      int r = __hip_atomic_fetch_add(gbase + 8 * 32, 1, __ATOMIC_RELAXED, __HIP_MEMORY_SCOPE_AGENT);
      if ((r & 7) == 7) {                         // root winner: broadcast epoch
        rootwin = true;
#pragma unroll
        for (int l = 0; l < 8; l++)
          st_u32_llc((unsigned int*)(gbase + (9 + l) * 32), (unsigned int)(g0l + 1));
      }
    }
    if (!rootwin) {
      while (ld_i32_llc(gbase + (9 + leaf) * 32) == g0l) __builtin_amdgcn_s_sleep(1);
    }
  }
  __syncthreads();
}

// ---------------- persistent recurrent kernel --------------------------------
// 512 WGs = 8 groups(16 samples) x 64 col-blocks; 2 blocks/CU co-resident.
// 4-wave K-partition: wave w owns kk w*8..w*8+7 (w<2: h via sc1, w>=2: x),
// computes BOTH col-halves, LDS-reduced; waves 0/1 run the epilogue.
template<int USE_XF>
__global__ void __launch_bounds__(256, 2)
lstm_kernel(const bf16_t* __restrict__ Xf, const bf16_t* __restrict__ A_sc,
            const bf16_t* __restrict__ Wb, const bf16_t* __restrict__ Bg,
            const float* __restrict__ bvec, const float* __restrict__ cbuf,
            bf16_t* __restrict__ Zb, float* __restrict__ S,
            float* __restrict__ out, int* __restrict__ bar,
            const float* __restrict__ x) {
  __shared__ bf16_t Wl[32768];        // 64KB [kk 0..31][wcH][64][8]
  __shared__ f32x4 red[4][2][64];     // 8KB per-wave partials (both col-halves)
  __shared__ float hsh[16 * 9];       // padded rows
  __shared__ float wls[16 * 17];      // padded rows

  const int wg = blockIdx.x, tid = threadIdx.x;
  const int cb = wg & 63, grp = wg >> 6;
  const int wave = tid >> 6, lane = tid & 63;
  const int s  = grp * 16 + (lane & 15);            // epilogue sample (wave<2)
  const int hcE = cb * 8 + wave * 4 + (lane >> 4);  // epilogue h-col (wave<2)
  const int jpE = cb * 32 + wave * 16 + (lane & 15);
  const float bias_l = (wave < 2) ? bvec[(jpE & 3) * H_ + (jpE >> 2)] : 0.f;
  const int jl = wave * 16 + (lane & 15);           // Bg col (wave<2)
  const int leaf = cb >> 3;
  int* gbase = bar + grp * 18 * 32;
  const int kkb = wave * 8;                         // this wave's global kk base

  // one-time LDS staging: W slice (64KB)
  {
    const bf16x8* src = (const bf16x8*)(Wb + (size_t)cb * WB_PER_CB);
    bf16x8* dst = (bf16x8*)Wl;
    for (int i = tid; i < 4096; i += 256) dst[i] = src[i];
  }
  float creg = (wave < 2) ? cbuf[s * H_ + hcE] : 0.f;   // c in register, all steps
  __syncthreads();

  int cur = 0;
  for (int t = 0; t < T_; t++) {
    const bf16_t* Zc = Zb + cur * ZB_ELEMS;
    bf16_t* Zn = Zb + (cur ^ 1) * ZB_ELEMS;
    const int cur3 = t % 3, nxt3 = (t + 1) % 3, z3 = (t + 2) % 3;

    // capture this episode's leaf epoch EARLY (== t here, proven invariant)
    int g0l = 0;
    if (tid == 0) g0l = ld_i32_llc(gbase + (9 + leaf) * 32);
    asm volatile("" ::: "memory");

    // zero group's S[(t+2)%3] slice: 4 floats per WG
    if (tid < 4) st_u32_llc((unsigned int*)(S + z3 * 2048 + grp * 256 + cb * 4 + tid), 0u);

    // fallback path only: stage x_{t+1} fragments into Zn
    if (!USE_XF && t + 1 < T_ && tid < 64) {
      int nl = tid >> 2, e2 = (tid & 3) * 2;
      int n = grp * 16 + nl;
      const float* xp = x + ((size_t)n * T_ + (t + 1)) * D_ + cb * 8 + e2;
      st_u32_llc((unsigned int*)(Zn + zidx(512 + cb * 8 + e2, n)), pack2bf(xp[0], xp[1]));
    }

    // issue this wave's 8 A-fragments FIRST (latency overlaps softmax below)
    bf16x8 afrag[8];
    if (USE_XF && wave >= 2) {
      const bf16x8* xf = (const bf16x8*)(Xf + (size_t)t * XF_PER_T);
#pragma unroll
      for (int i = 0; i < 8; i++)
        afrag[i] = xf[((kkb - 16 + i) * 8 + grp) * 64 + lane];
    } else {
#pragma unroll
      for (int i = 0; i < 8; i++)
        afrag[i] = ld_frag_llc(Zc + ((size_t)((kkb + i) * 8 + grp) * 64 + lane) * 8);
    }

    // softmax: 16 lanes (4 per wave), one sample each
    if ((tid & 63) < 4) {
      int nl = wave * 4 + (tid & 63);
      int ng = grp * 16 + nl;
      float r[16];
#pragma unroll
      for (int p = 0; p < 16; p++)
        r[p] = ld_f32_llc(S + cur3 * 2048 + ng * 16 + p) * 0.044194173824159216f;
      float m = r[0];
#pragma unroll
      for (int p = 1; p < 16; p++) m = fmaxf(m, r[p]);
      float ssum = 0.f;
#pragma unroll
      for (int p = 0; p < 16; p++) { r[p] = __expf(r[p] - m); ssum += r[p]; }
      float inv = 1.f / ssum;
#pragma unroll
      for (int p = 0; p < 16; p++) wls[nl * 17 + p] = r[p] * inv;
    }

    // MFMA: this wave's 8 kk x both col-halves
    f32x4 acc0 = {0.f, 0.f, 0.f, 0.f}, acc1 = {0.f, 0.f, 0.f, 0.f};
    {
      const bf16x8* Wf = (const bf16x8*)Wl;
#pragma unroll
      for (int i = 0; i < 8; i++) {
        int kk = kkb + i;
        acc0 = __builtin_amdgcn_mfma_f32_16x16x32_bf16(afrag[i], Wf[(kk * 2 + 0) * 64 + lane], acc0, 0, 0, 0);
        acc1 = __builtin_amdgcn_mfma_f32_16x16x32_bf16(afrag[i], Wf[(kk * 2 + 1) * 64 + lane], acc1, 0, 0, 0);
      }
    }
    red[wave][0][lane] = acc0;
    red[wave][1][lane] = acc1;
    __syncthreads();   // red + wls ready

    if (wave < 2) {
      f32x4 fa = red[0][wave][lane];
#pragma unroll
      for (int w = 1; w < 4; w++) {
        f32x4 o = red[w][wave][lane];
        fa[0] += o[0]; fa[1] += o[1]; fa[2] += o[2]; fa[3] += o[3];
      }
      // + w@B + bias (acc row rp = sample (lane>>4)*4+rp); Bg L2-warm
      const int nl0 = (lane >> 4) << 2;
#pragma unroll
      for (int rp = 0; rp < 4; rp++) {
        int nl = nl0 + rp;
        const bf16x8* bl = (const bf16x8*)(Bg +
            (((size_t)(grp * 16 + nl) * 64 + cb) * 32 + jl) * 16);
        bf16x8 b0 = bl[0], b1 = bl[1];
        const float* wn = wls + nl * 17;
        float add = 0.f;
#pragma unroll
        for (int p = 0; p < 8; p++) add += wn[p] * (float)b0[p];
#pragma unroll
        for (int p = 0; p < 8; p++) add += wn[8 + p] * (float)b1[p];
        fa[rp] += add + bias_l;
      }

      // gather i,f,o,g quads (within-wave shuffle)
      float gv[4] = {0.f, 0.f, 0.f, 0.f};
      const int srcbase = ((lane >> 2) & 3) * 16 + (lane >> 4) * 4;
#pragma unroll
      for (int rp = 0; rp < 4; rp++) {
        float v = fa[rp];
#pragma unroll
        for (int g = 0; g < 4; g++) {
          float sv = __shfl(v, srcbase + g, 64);
          if ((lane & 3) == rp) gv[g] = sv;
        }
      }

      // gates, state update, outputs
      float si = sigf(gv[0]), sf = sigf(gv[1]), so = sigf(gv[2]);
      float cn = sf * creg + si * tanhfast(gv[3]);
      float hn = so * tanhfast(cn);
      creg = cn;
      __builtin_nontemporal_store(hn, out + ((size_t)s * T_ + t) * H_ + hcE);

      // h_{t+1} to Zn (paired bf16 -> u32 sc1 store)
      union { bf16_t h; unsigned short u; } cvt; cvt.h = (bf16_t)hn;
      unsigned int hbits = cvt.u;
      unsigned int other = __shfl(hbits, (lane + 16) & 63, 64);
      if (((lane >> 4) & 1) == 0)
        st_u32_llc((unsigned int*)(Zn + zidx(hcE, s)), hbits | (other << 16));
      hsh[(s & 15) * 9 + (hcE & 7)] = hn;
    }
    __syncthreads();   // hsh ready

    // partial scores for t+1: 256 threads, one (sample,p) each, dot over 8 hc
    if (t + 1 < T_) {
      int nl = tid >> 4, p = tid & 15;
      int ng = grp * 16 + nl;
      const bf16x8 av = *(const bf16x8*)(A_sc + ((size_t)ng * 64 + cb) * 128 + p * 8);
      float part = 0.f;
#pragma unroll
      for (int c = 0; c < 8; c++) part += hsh[nl * 9 + c] * (float)av[c];
      atomicAdd(S + nxt3 * 2048 + ng * 16 + p, part);   // agent-scope, at LLC
    }

    gridbar(gbase, leaf, g0l);
    cur ^= 1;
  }
}

// ---------------- host ----------------
extern "C" void kernel_launch(void* const* d_in, const int* in_sizes, int n_in,
                              void* d_out, int out_size, void* d_ws, size_t ws_size,
                              hipStream_t stream) {
  const float* x     = (const float*)d_in[0];
  const float* A     = (const float*)d_in[1];
  const float* Wx    = (const float*)d_in[2];
  const float* Wh    = (const float*)d_in[3];
  const float* Wattn = (const float*)d_in[4];
  const float* bv    = (const float*)d_in[5];
  float* out = (float*)d_out;

  char* ws = (char*)d_ws;
  // ws layout (bytes) — sync state FIRST so array overflows can't corrupt it
  const size_t BAR_OFF = 0;          // 8 grp * 18 lines * 128B (pad 32768)
  const size_t S_OFF   = 32768;      // 3*2048*4        = 24576
  const size_t CB_OFF  = 57344;      // 128*512*4       = 262144
  const size_t ZB_OFF  = 319488;     // 2*131072*2      = 524288
  const size_t ASC_OFF = 843776;     // 128*8192*2      = 2097152
  const size_t WB_OFF  = 2940928;    // 64*32768*2      = 4194304
  const size_t BG_OFF  = 7135232;    // 128*64*32*16 el * 2B = 8388608
  const size_t XF_OFF  = 15523840;   // 256*65536 el * 2B = 33554432
  const size_t WS_BASE = 15523840;
  const size_t WS_XF   = 49078272;   // XF_OFF + 33554432
  if (ws_size < WS_BASE) return;     // clean fail instead of corruption
  const bool use_xf = (ws_size >= WS_XF);

  int*    bar  = (int*)(ws + BAR_OFF);
  float*  S    = (float*)(ws + S_OFF);
  float*  cbuf = (float*)(ws + CB_OFF);
  bf16_t* Zb   = (bf16_t*)(ws + ZB_OFF);
  bf16_t* A_sc = (bf16_t*)(ws + ASC_OFF);
  bf16_t* Wb   = (bf16_t*)(ws + WB_OFF);
  bf16_t* Bg   = (bf16_t*)(ws + BG_OFF);
  bf16_t* Xf   = (bf16_t*)(ws + XF_OFF);

  prepW_kernel<<<dim3(128), dim3(256), 0, stream>>>(Wh, Wx, Wb);
  prepA_kernel<<<dim3(128), dim3(256), 0, stream>>>(A, x, A_sc, cbuf, Zb, S, bar);
  prepB_kernel<<<dim3(512), dim3(256), 0, stream>>>(Wattn, A_sc, Bg);
  if (use_xf) {
    prepX_kernel<<<dim3(8192), dim3(256), 0, stream>>>(x, Xf);
    lstm_kernel<1><<<dim3(512), dim3(256), 0, stream>>>(Xf, A_sc, Wb, Bg, bv, cbuf, Zb, S, out, bar, x);
  } else {
    lstm_kernel<0><<<dim3(512), dim3(256), 0, stream>>>(Xf, A_sc, Wb, Bg, bv, cbuf, Zb, S, out, bar, x);
  }
}

// Round 11
// 1901.742 us; speedup vs baseline: 7.6895x; 1.0232x over previous
//
#include <hip/hip_runtime.h>
#include <hip/hip_bf16.h>

typedef __bf16 bf16_t;
typedef __bf16 bf16x8 __attribute__((ext_vector_type(8)));
typedef float  f32x4  __attribute__((ext_vector_type(4)));

#define N_    128
#define T_    256
#define D_    512
#define H_    512
#define G4    2048
#define ZB_ELEMS 131072   /* full-K Z buffer: 32kk*8nb*64*8 (x half unused in Xf mode) */
#define XF_PER_T 65536    /* 16kk*8nb*64*8 = 128x512 x-fragments per step */
#define WB_PER_CB 32768   /* 1024*32 */

// fragment-ordered index: k in [0,1024), n in [0,128)
__device__ __forceinline__ int zidx(int k, int n) {
  return ((((k >> 5) * 8 + (n >> 4)) * 64) + ((k >> 3) & 3) * 16 + (n & 15)) * 8 + (k & 7);
}

__device__ __forceinline__ float sigf(float x) { return 1.f / (1.f + __expf(-x)); }
__device__ __forceinline__ float tanhfast(float x) {
  float e = __expf(2.f * x);
  return 1.f - 2.f / (e + 1.f);
}

// ---- LLC-coherent access (agent-scope relaxed atomics -> sc1, no L2 wb/inv) ----
__device__ __forceinline__ bf16x8 ld_frag_llc(const bf16_t* p) {
  unsigned long long lo = __hip_atomic_load((const unsigned long long*)p,
      __ATOMIC_RELAXED, __HIP_MEMORY_SCOPE_AGENT);
  unsigned long long hi = __hip_atomic_load(((const unsigned long long*)p) + 1,
      __ATOMIC_RELAXED, __HIP_MEMORY_SCOPE_AGENT);
  union { unsigned long long q[2]; bf16x8 v; } u; u.q[0] = lo; u.q[1] = hi; return u.v;
}
__device__ __forceinline__ float ld_f32_llc(const float* p) {
  return __hip_atomic_load(p, __ATOMIC_RELAXED, __HIP_MEMORY_SCOPE_AGENT);
}
__device__ __forceinline__ void st_u32_llc(unsigned int* p, unsigned int v) {
  __hip_atomic_store(p, v, __ATOMIC_RELAXED, __HIP_MEMORY_SCOPE_AGENT);
}
__device__ __forceinline__ int ld_i32_llc(const int* p) {
  return __hip_atomic_load(p, __ATOMIC_RELAXED, __HIP_MEMORY_SCOPE_AGENT);
}
__device__ __forceinline__ unsigned int pack2bf(float lo, float hi) {
  union { bf16_t h[2]; unsigned int u; } q;
  q.h[0] = (bf16_t)lo; q.h[1] = (bf16_t)hi; return q.u;
}

// ---------------- prep: weights to fragment order (Wh rows 0..512, Wx 512..1024) --
__global__ void prepW_kernel(const float* __restrict__ Wh, const float* __restrict__ Wx,
                             bf16_t* __restrict__ Wb) {
  int cb = blockIdx.x >> 1, kq = blockIdx.x & 1;
  int tt = threadIdx.x;
  int hl = tt & 7, gate = (tt >> 3) & 3, ko = tt >> 5;
  int oc = gate * H_ + cb * 8 + hl;
  int jpl = hl * 4 + gate;
  int wcl = jpl >> 4, c = jpl & 15;
  for (int kb = kq * 64; kb < kq * 64 + 64; kb++) {
    int k = kb * 8 + ko;
    float v = (k < 512) ? Wh[(size_t)k * G4 + oc] : Wx[(size_t)(k - 512) * G4 + oc];
    int kk = k >> 5, ch = (k >> 3) & 3, e = k & 7;
    Wb[(size_t)cb * WB_PER_CB + (((kk * 2 + wcl) * 64) + ch * 16 + c) * 8 + e] = (bf16_t)v;
  }
}

// ---------------- prep: x fragments for ALL steps (read-only in loop) -----------
__global__ void prepX_kernel(const float* __restrict__ x, bf16_t* __restrict__ Xf) {
  int gid = blockIdx.x * 256 + threadIdx.x;   // 8192 blocks
  int e8 = gid & 63;                          // k = e8*8 .. +7
  int n  = (gid >> 6) & 127;
  int t  = gid >> 13;
  int k  = e8 * 8;
  const float* xp = x + ((size_t)n * T_ + t) * D_ + k;
  union { bf16_t b[8]; bf16x8 v; } u;
#pragma unroll
  for (int e = 0; e < 8; e++) u.b[e] = (bf16_t)xp[e];
  int idx = ((k >> 5) * 8 + (n >> 4)) * 64 + ((k >> 3) & 3) * 16 + (n & 15);
  ((bf16x8*)(Xf + (size_t)t * XF_PER_T))[idx] = u.v;
}

// ---------------- prep: A_sc layout, h0/c0, Zb[0] h+x, S[0] scores, S[1]=0, bar ----
__global__ void prepA_kernel(const float* __restrict__ A, const float* __restrict__ x,
                             bf16_t* __restrict__ A_sc, float* __restrict__ cbuf,
                             bf16_t* __restrict__ Zb, float* __restrict__ S,
                             int* __restrict__ bar) {
  __shared__ float a_ld[8192];   // A[n]: [h][p] f32, 32KB
  __shared__ float h0s[512];
  __shared__ float redb[256 * 16];
  int n = blockIdx.x, tid = threadIdx.x;
  if (n == 0 && tid < 144) bar[tid * 32] = 0;   // 8 groups x 18 lines
  if (tid < 16) S[2048 + n * 16 + tid] = 0.f;   // zero S[1]
  for (int i = tid; i < 8192; i += 256) a_ld[i] = A[(size_t)n * 8192 + i];
  __syncthreads();
  for (int h = tid; h < H_; h += 256) {
    float s = 0.f;
#pragma unroll
    for (int p = 0; p < 16; p++) s += a_ld[h * 16 + p];
    s *= (1.f / 16.f);
    h0s[h] = s;
    cbuf[n * H_ + h] = s;
    Zb[zidx(h, n)] = (bf16_t)s;
  }
  // x for t=0 (used only by the non-Xf fallback path; cheap, unconditional)
  for (int d = tid; d < D_; d += 256)
    Zb[zidx(512 + d, n)] = (bf16_t)x[(size_t)n * T_ * D_ + d];
  // A_sc[n][cb][p][c] = A[n][cb*8+c][p]
  for (int idx = tid; idx < 8192; idx += 256) {
    int k = idx >> 4, p = idx & 15;
    A_sc[(size_t)n * 8192 + ((k >> 3) * 16 + p) * 8 + (k & 7)] = (bf16_t)a_ld[idx];
  }
  __syncthreads();
  // S[0][n][p] = sum_h h0[h]*A[n][h][p]  (raw, scale applied in softmax)
  float part[16];
#pragma unroll
  for (int p = 0; p < 16; p++) part[p] = 0.f;
  for (int h = tid; h < H_; h += 256) {
    float hv = h0s[h];
#pragma unroll
    for (int p = 0; p < 16; p++) part[p] += hv * a_ld[h * 16 + p];
  }
#pragma unroll
  for (int p = 0; p < 16; p++) redb[tid * 16 + p] = part[p];
  __syncthreads();
  if (tid < 16) {
    float s = 0.f;
    for (int i = 0; i < 256; i++) s += redb[i * 16 + tid];
    S[n * 16 + tid] = s;
  }
}

// ---------------- prep: B[n,p,j] = sum_h A[n,h,p]*Wattn[h,j], stored [n][cb][jl][p] --
__global__ void __launch_bounds__(256) prepB_kernel(const float* __restrict__ Wattn,
                             const bf16_t* __restrict__ A_sc, bf16_t* __restrict__ Bg) {
  __shared__ bf16_t Al[8192];   // [cb][p][c] = 1024 bf16x8 (FULLY staged)
  int n = blockIdx.x >> 2, jpQ = blockIdx.x & 3;
  int tid = threadIdx.x, p = tid & 15, jg = tid >> 4;
  for (int i = tid; i < 1024; i += 256)
    ((bf16x8*)Al)[i] = ((const bf16x8*)(A_sc + (size_t)n * 8192))[i];
  __syncthreads();
  int cbb = jpQ * 16 + jg;
  float acc[32];
#pragma unroll
  for (int j = 0; j < 32; j++) acc[j] = 0.f;
  for (int k = 0; k < 512; k++) {
    float a = (float)Al[((k >> 3) * 16 + p) * 8 + (k & 7)];
    const float* wr = Wattn + (size_t)k * G4 + cbb * 8;
#pragma unroll
    for (int gate = 0; gate < 4; gate++) {
      const float4* w4 = (const float4*)(wr + gate * H_);
      float4 wa = w4[0], wb = w4[1];
      acc[0 * 4 + gate] += a * wa.x; acc[1 * 4 + gate] += a * wa.y;
      acc[2 * 4 + gate] += a * wa.z; acc[3 * 4 + gate] += a * wa.w;
      acc[4 * 4 + gate] += a * wb.x; acc[5 * 4 + gate] += a * wb.y;
      acc[6 * 4 + gate] += a * wb.z; acc[7 * 4 + gate] += a * wb.w;
    }
  }
  bf16_t* dst = Bg + (((size_t)n * 64 + cbb) * 32) * 16 + p;
#pragma unroll
  for (int jj = 0; jj < 32; jj++) dst[jj * 16] = (bf16_t)acc[jj];
}

// ---- per-group fence-free barrier, 64 WGs, 8x8 tree, DIRECT root broadcast ----
// gbase lines (x32 ints): leafctr[0..7], rootctr(8), gen_leaf[9..16]
__device__ __forceinline__ void gridbar(int* gbase, int leaf, int g0l) {
  __syncthreads();   // vmcnt(0): all this block's sc1 stores are in LLC
  if (threadIdx.x == 0) {
    int my = __hip_atomic_fetch_add(gbase + leaf * 32, 1, __ATOMIC_RELAXED, __HIP_MEMORY_SCOPE_AGENT);
    bool rootwin = false;
    if ((my & 7) == 7) {                          // leaf winner
      int r = __hip_atomic_fetch_add(gbase + 8 * 32, 1, __ATOMIC_RELAXED, __HIP_MEMORY_SCOPE_AGENT);
      if ((r & 7) == 7) {                         // root winner: broadcast epoch
        rootwin = true;
#pragma unroll
        for (int l = 0; l < 8; l++)
          st_u32_llc((unsigned int*)(gbase + (9 + l) * 32), (unsigned int)(g0l + 1));
      }
    }
    if (!rootwin) {
      while (ld_i32_llc(gbase + (9 + leaf) * 32) == g0l) __builtin_amdgcn_s_sleep(1);
    }
  }
  __syncthreads();
}

// ---------------- persistent recurrent kernel --------------------------------
// 512 WGs = 8 groups(16 samples) x 64 col-blocks.
// R11: grp/cb remap so CO-RESIDENT blocks (any pairing: +1, +8 per-XCD, +256
// second-pass) belong to DIFFERENT groups -> their independent barriers drift
// anti-phase and hide each other's wait. Bijective: for fixed cb, wg&7 spans
// all 8 grp values. Bg/A_sc/Wb slices are private per (grp,cb) so no L2
// locality is lost by the remap; Z/S live in LLC (placement-neutral).
template<int USE_XF>
__global__ void __launch_bounds__(256, 2)
lstm_kernel(const bf16_t* __restrict__ Xf, const bf16_t* __restrict__ A_sc,
            const bf16_t* __restrict__ Wb, const bf16_t* __restrict__ Bg,
            const float* __restrict__ bvec, const float* __restrict__ cbuf,
            bf16_t* __restrict__ Zb, float* __restrict__ S,
            float* __restrict__ out, int* __restrict__ bar,
            const float* __restrict__ x) {
  __shared__ bf16_t Wl[32768];        // 64KB [kk 0..31][wcH][64][8]
  __shared__ f32x4 red[4][2][64];     // 8KB per-wave partials (both col-halves)
  __shared__ float hsh[16 * 9];       // padded rows
  __shared__ float wls[16 * 17];      // padded rows

  const int wg = blockIdx.x, tid = threadIdx.x;
  const int cb = wg >> 3;                                   // R11 remap
  const int grp = (wg & 7) ^ ((wg >> 3) & 7) ^ ((wg >> 6) & 7);   // R11 remap
  const int wave = tid >> 6, lane = tid & 63;
  const int s  = grp * 16 + (lane & 15);            // epilogue sample (wave<2)
  const int hcE = cb * 8 + wave * 4 + (lane >> 4);  // epilogue h-col (wave<2)
  const int jpE = cb * 32 + wave * 16 + (lane & 15);
  const float bias_l = (wave < 2) ? bvec[(jpE & 3) * H_ + (jpE >> 2)] : 0.f;
  const int jl = wave * 16 + (lane & 15);           // Bg col (wave<2)
  const int leaf = cb >> 3;
  int* gbase = bar + grp * 18 * 32;
  const int kkb = wave * 8;                         // this wave's global kk base

  // one-time LDS staging: W slice (64KB)
  {
    const bf16x8* src = (const bf16x8*)(Wb + (size_t)cb * WB_PER_CB);
    bf16x8* dst = (bf16x8*)Wl;
    for (int i = tid; i < 4096; i += 256) dst[i] = src[i];
  }
  float creg = (wave < 2) ? cbuf[s * H_ + hcE] : 0.f;   // c in register, all steps
  __syncthreads();

  int cur = 0;
  for (int t = 0; t < T_; t++) {
    const bf16_t* Zc = Zb + cur * ZB_ELEMS;
    bf16_t* Zn = Zb + (cur ^ 1) * ZB_ELEMS;
    const int cur3 = t % 3, nxt3 = (t + 1) % 3, z3 = (t + 2) % 3;

    // capture this episode's leaf epoch EARLY (== t here, proven invariant)
    int g0l = 0;
    if (tid == 0) g0l = ld_i32_llc(gbase + (9 + leaf) * 32);
    asm volatile("" ::: "memory");

    // zero group's S[(t+2)%3] slice: 4 floats per WG
    if (tid < 4) st_u32_llc((unsigned int*)(S + z3 * 2048 + grp * 256 + cb * 4 + tid), 0u);

    // fallback path only: stage x_{t+1} fragments into Zn
    if (!USE_XF && t + 1 < T_ && tid < 64) {
      int nl = tid >> 2, e2 = (tid & 3) * 2;
      int n = grp * 16 + nl;
      const float* xp = x + ((size_t)n * T_ + (t + 1)) * D_ + cb * 8 + e2;
      st_u32_llc((unsigned int*)(Zn + zidx(512 + cb * 8 + e2, n)), pack2bf(xp[0], xp[1]));
    }

    // issue this wave's 8 A-fragments FIRST (latency overlaps softmax below)
    bf16x8 afrag[8];
    if (USE_XF && wave >= 2) {
      const bf16x8* xf = (const bf16x8*)(Xf + (size_t)t * XF_PER_T);
#pragma unroll
      for (int i = 0; i < 8; i++)
        afrag[i] = xf[((kkb - 16 + i) * 8 + grp) * 64 + lane];
    } else {
#pragma unroll
      for (int i = 0; i < 8; i++)
        afrag[i] = ld_frag_llc(Zc + ((size_t)((kkb + i) * 8 + grp) * 64 + lane) * 8);
    }

    // softmax: 16 lanes (4 per wave), one sample each
    if ((tid & 63) < 4) {
      int nl = wave * 4 + (tid & 63);
      int ng = grp * 16 + nl;
      float r[16];
#pragma unroll
      for (int p = 0; p < 16; p++)
        r[p] = ld_f32_llc(S + cur3 * 2048 + ng * 16 + p) * 0.044194173824159216f;
      float m = r[0];
#pragma unroll
      for (int p = 1; p < 16; p++) m = fmaxf(m, r[p]);
      float ssum = 0.f;
#pragma unroll
      for (int p = 0; p < 16; p++) { r[p] = __expf(r[p] - m); ssum += r[p]; }
      float inv = 1.f / ssum;
#pragma unroll
      for (int p = 0; p < 16; p++) wls[nl * 17 + p] = r[p] * inv;
    }

    // MFMA: this wave's 8 kk x both col-halves
    f32x4 acc0 = {0.f, 0.f, 0.f, 0.f}, acc1 = {0.f, 0.f, 0.f, 0.f};
    {
      const bf16x8* Wf = (const bf16x8*)Wl;
#pragma unroll
      for (int i = 0; i < 8; i++) {
        int kk = kkb + i;
        acc0 = __builtin_amdgcn_mfma_f32_16x16x32_bf16(afrag[i], Wf[(kk * 2 + 0) * 64 + lane], acc0, 0, 0, 0);
        acc1 = __builtin_amdgcn_mfma_f32_16x16x32_bf16(afrag[i], Wf[(kk * 2 + 1) * 64 + lane], acc1, 0, 0, 0);
      }
    }
    red[wave][0][lane] = acc0;
    red[wave][1][lane] = acc1;
    __syncthreads();   // red + wls ready

    if (wave < 2) {
      f32x4 fa = red[0][wave][lane];
#pragma unroll
      for (int w = 1; w < 4; w++) {
        f32x4 o = red[w][wave][lane];
        fa[0] += o[0]; fa[1] += o[1]; fa[2] += o[2]; fa[3] += o[3];
      }
      // + w@B + bias (acc row rp = sample (lane>>4)*4+rp); Bg L2-warm
      const int nl0 = (lane >> 4) << 2;
#pragma unroll
      for (int rp = 0; rp < 4; rp++) {
        int nl = nl0 + rp;
        const bf16x8* bl = (const bf16x8*)(Bg +
            (((size_t)(grp * 16 + nl) * 64 + cb) * 32 + jl) * 16);
        bf16x8 b0 = bl[0], b1 = bl[1];
        const float* wn = wls + nl * 17;
        float add = 0.f;
#pragma unroll
        for (int p = 0; p < 8; p++) add += wn[p] * (float)b0[p];
#pragma unroll
        for (int p = 0; p < 8; p++) add += wn[8 + p] * (float)b1[p];
        fa[rp] += add + bias_l;
      }

      // gather i,f,o,g quads (within-wave shuffle)
      float gv[4] = {0.f, 0.f, 0.f, 0.f};
      const int srcbase = ((lane >> 2) & 3) * 16 + (lane >> 4) * 4;
#pragma unroll
      for (int rp = 0; rp < 4; rp++) {
        float v = fa[rp];
#pragma unroll
        for (int g = 0; g < 4; g++) {
          float sv = __shfl(v, srcbase + g, 64);
          if ((lane & 3) == rp) gv[g] = sv;
        }
      }

      // gates, state update, outputs
      float si = sigf(gv[0]), sf = sigf(gv[1]), so = sigf(gv[2]);
      float cn = sf * creg + si * tanhfast(gv[3]);
      float hn = so * tanhfast(cn);
      creg = cn;
      __builtin_nontemporal_store(hn, out + ((size_t)s * T_ + t) * H_ + hcE);

      // h_{t+1} to Zn (paired bf16 -> u32 sc1 store)
      union { bf16_t h; unsigned short u; } cvt; cvt.h = (bf16_t)hn;
      unsigned int hbits = cvt.u;
      unsigned int other = __shfl(hbits, (lane + 16) & 63, 64);
      if (((lane >> 4) & 1) == 0)
        st_u32_llc((unsigned int*)(Zn + zidx(hcE, s)), hbits | (other << 16));
      hsh[(s & 15) * 9 + (hcE & 7)] = hn;
    }
    __syncthreads();   // hsh ready

    // partial scores for t+1: 256 threads, one (sample,p) each, dot over 8 hc
    if (t + 1 < T_) {
      int nl = tid >> 4, p = tid & 15;
      int ng = grp * 16 + nl;
      const bf16x8 av = *(const bf16x8*)(A_sc + ((size_t)ng * 64 + cb) * 128 + p * 8);
      float part = 0.f;
#pragma unroll
      for (int c = 0; c < 8; c++) part += hsh[nl * 9 + c] * (float)av[c];
      atomicAdd(S + nxt3 * 2048 + ng * 16 + p, part);   // agent-scope, at LLC
    }

    gridbar(gbase, leaf, g0l);
    cur ^= 1;
  }
}

// ---------------- host ----------------
extern "C" void kernel_launch(void* const* d_in, const int* in_sizes, int n_in,
                              void* d_out, int out_size, void* d_ws, size_t ws_size,
                              hipStream_t stream) {
  const float* x     = (const float*)d_in[0];
  const float* A     = (const float*)d_in[1];
  const float* Wx    = (const float*)d_in[2];
  const float* Wh    = (const float*)d_in[3];
  const float* Wattn = (const float*)d_in[4];
  const float* bv    = (const float*)d_in[5];
  float* out = (float*)d_out;

  char* ws = (char*)d_ws;
  // ws layout (bytes) — sync state FIRST so array overflows can't corrupt it
  const size_t BAR_OFF = 0;          // 8 grp * 18 lines * 128B (pad 32768)
  const size_t S_OFF   = 32768;      // 3*2048*4        = 24576
  const size_t CB_OFF  = 57344;      // 128*512*4       = 262144
  const size_t ZB_OFF  = 319488;     // 2*131072*2      = 524288
  const size_t ASC_OFF = 843776;     // 128*8192*2      = 2097152
  const size_t WB_OFF  = 2940928;    // 64*32768*2      = 4194304
  const size_t BG_OFF  = 7135232;    // 128*64*32*16 el * 2B = 8388608
  const size_t XF_OFF  = 15523840;   // 256*65536 el * 2B = 33554432
  const size_t WS_BASE = 15523840;
  const size_t WS_XF   = 49078272;   // XF_OFF + 33554432
  if (ws_size < WS_BASE) return;     // clean fail instead of corruption
  const bool use_xf = (ws_size >= WS_XF);

  int*    bar  = (int*)(ws + BAR_OFF);
  float*  S    = (float*)(ws + S_OFF);
  float*  cbuf = (float*)(ws + CB_OFF);
  bf16_t* Zb   = (bf16_t*)(ws + ZB_OFF);
  bf16_t* A_sc = (bf16_t*)(ws + ASC_OFF);
  bf16_t* Wb   = (bf16_t*)(ws + WB_OFF);
  bf16_t* Bg   = (bf16_t*)(ws + BG_OFF);
  bf16_t* Xf   = (bf16_t*)(ws + XF_OFF);

  prepW_kernel<<<dim3(128), dim3(256), 0, stream>>>(Wh, Wx, Wb);
  prepA_kernel<<<dim3(128), dim3(256), 0, stream>>>(A, x, A_sc, cbuf, Zb, S, bar);
  prepB_kernel<<<dim3(512), dim3(256), 0, stream>>>(Wattn, A_sc, Bg);
  if (use_xf) {
    prepX_kernel<<<dim3(8192), dim3(256), 0, stream>>>(x, Xf);
    lstm_kernel<1><<<dim3(512), dim3(256), 0, stream>>>(Xf, A_sc, Wb, Bg, bv, cbuf, Zb, S, out, bar, x);
  } else {
    lstm_kernel<0><<<dim3(512), dim3(256), 0, stream>>>(Xf, A_sc, Wb, Bg, bv, cbuf, Zb, S, out, bar, x);
  }
}